// Round 2
// baseline (52005.579 us; speedup 1.0000x reference)
//
#include <hip/hip_runtime.h>
#include <cstdint>
#include <cstddef>

// G=256 graphs, NP=1000 points, K=8 neighbors, H=8 heads, DH=10, D=80, NL=10 layers

// 4 rows x 40 k-elements (one k-half), wcol[40] in registers
__device__ __forceinline__ void dot4x40(const float* __restrict__ in, int strideF,
                                        const float* __restrict__ wcol, float acc[4]) {
  #pragma unroll
  for (int j = 0; j < 4; ++j) {
    const float4* r4 = reinterpret_cast<const float4*>(in + j * strideF);
    #pragma unroll
    for (int kq = 0; kq < 10; ++kq) {
      float4 hv = r4[kq];
      acc[j] = fmaf(hv.x, wcol[4 * kq + 0], acc[j]);
      acc[j] = fmaf(hv.y, wcol[4 * kq + 1], acc[j]);
      acc[j] = fmaf(hv.z, wcol[4 * kq + 2], acc[j]);
      acc[j] = fmaf(hv.w, wcol[4 * kq + 3], acc[j]);
    }
  }
}

// ---------------- KNN: exact reference-order arithmetic, stable tie-break ----------------
__global__ __launch_bounds__(256) void knn_kernel(const float* __restrict__ hf, int* __restrict__ nbr) {
  __shared__ float cs[3000];
  int b = blockIdx.x;
  int g = b >> 2;
  int q = b & 3;
  for (int i = threadIdx.x; i < 3000; i += 256) {
    cs[i] = hf[((size_t)g * 1000 + (i / 3)) * 9 + (i % 3)];
  }
  __syncthreads();
  int tid = threadIdx.x;
  if (tid < 250) {
    int n = q * 250 + tid;
    float cx = cs[n * 3 + 0], cy = cs[n * 3 + 1], cz = cs[n * 3 + 2];
    float bd[8];
    int bi[8];
    #pragma unroll
    for (int q2 = 0; q2 < 8; ++q2) { bd[q2] = 3.402823466e38f; bi[q2] = 0; }
    for (int j = 0; j < 1000; ++j) {
      float dx = __fsub_rn(cx, cs[j * 3 + 0]);
      float dy = __fsub_rn(cy, cs[j * 3 + 1]);
      float dz = __fsub_rn(cz, cs[j * 3 + 2]);
      float d2 = __fadd_rn(__fadd_rn(__fmul_rn(dx, dx), __fmul_rn(dy, dy)), __fmul_rn(dz, dz));
      if (d2 < bd[7]) {
        bd[7] = d2; bi[7] = j;
        #pragma unroll
        for (int q2 = 7; q2 >= 1; --q2) {
          if (bd[q2] < bd[q2 - 1]) {
            float tf = bd[q2]; bd[q2] = bd[q2 - 1]; bd[q2 - 1] = tf;
            int ti = bi[q2]; bi[q2] = bi[q2 - 1]; bi[q2 - 1] = ti;
          }
        }
      }
    }
    #pragma unroll
    for (int kk = 0; kk < 8; ++kk) nbr[((size_t)g * 1000 + n) * 8 + kk] = bi[kk];
  }
}

// ---------------- BatchNorm stats (deterministic two-stage) ----------------
__global__ __launch_bounds__(256) void bn_stat1(const float* __restrict__ hf, float* __restrict__ partial) {
  __shared__ float red[4][18];
  int row = blockIdx.x * 256 + threadIdx.x;
  float s[9], ss[9];
  #pragma unroll
  for (int f = 0; f < 9; ++f) {
    float v = hf[(size_t)row * 9 + f];
    s[f] = v;
    ss[f] = v * v;
  }
  for (int off = 32; off > 0; off >>= 1) {
    #pragma unroll
    for (int f = 0; f < 9; ++f) {
      s[f] += __shfl_down(s[f], off);
      ss[f] += __shfl_down(ss[f], off);
    }
  }
  int wid = threadIdx.x >> 6, lane = threadIdx.x & 63;
  if (lane == 0) {
    #pragma unroll
    for (int f = 0; f < 9; ++f) { red[wid][f] = s[f]; red[wid][9 + f] = ss[f]; }
  }
  __syncthreads();
  if (threadIdx.x < 18) {
    partial[(size_t)blockIdx.x * 18 + threadIdx.x] =
        red[0][threadIdx.x] + red[1][threadIdx.x] + red[2][threadIdx.x] + red[3][threadIdx.x];
  }
}

__global__ __launch_bounds__(256) void bn_stat2(const float* __restrict__ partial, float* __restrict__ stats) {
  __shared__ double sd[9][28], qd[9][28];
  int tid = threadIdx.x;
  if (tid < 252) {
    int f = tid % 9, gq = tid / 9;
    double s = 0.0, q = 0.0;
    for (int b = gq; b < 1000; b += 28) {
      s += (double)partial[b * 18 + f];
      q += (double)partial[b * 18 + 9 + f];
    }
    sd[f][gq] = s;
    qd[f][gq] = q;
  }
  __syncthreads();
  if (tid < 9) {
    double s = 0.0, q = 0.0;
    for (int g2 = 0; g2 < 28; ++g2) { s += sd[tid][g2]; q += qd[tid][g2]; }
    double mu = s / 256000.0;
    double var = q / 256000.0 - mu * mu;
    stats[tid] = (float)mu;
    stats[9 + tid] = (float)(1.0 / sqrt(var + 1e-5));
  }
}

// ---------------- Embed: normalize + (9->80) ----------------
__global__ __launch_bounds__(320) void embed_kernel(const float* __restrict__ hf, const float* __restrict__ stats,
                                                    const float* __restrict__ gamma, const float* __restrict__ beta,
                                                    const float* __restrict__ We, const float* __restrict__ be,
                                                    float* __restrict__ h) {
  __shared__ __align__(16) float xs[40 * 9];
  size_t p0 = (size_t)blockIdx.x * 40;
  for (int i = threadIdx.x; i < 360; i += 320) {
    int f = i % 9;
    float x = hf[p0 * 9 + i];
    xs[i] = (x - stats[f]) * stats[9 + f] * gamma[f] + beta[f];
  }
  __syncthreads();
  int c = threadIdx.x % 80, pg = threadIdx.x / 80;
  float we[9];
  #pragma unroll
  for (int f = 0; f < 9; ++f) we[f] = We[f * 80 + c];
  float bias = be[c];
  for (int pp = 0; pp < 10; ++pp) {
    int p = pg * 10 + pp;
    float acc = 0.f;
    #pragma unroll
    for (int f = 0; f < 9; ++f) acc = fmaf(xs[p * 9 + f], we[f], acc);
    h[(p0 + p) * 80 + c] = acc + bias;
  }
}

// ---------------- K,V projection (k-split registers) ----------------
__global__ __launch_bounds__(320, 5) void kv_kernel(const float* __restrict__ h, const float* __restrict__ Wk,
                                                    const float* __restrict__ Wv, float* __restrict__ kb,
                                                    float* __restrict__ vb) {
  __shared__ __align__(16) float hs[3200];
  size_t p0 = (size_t)blockIdx.x * 40;
  {
    const float4* src = reinterpret_cast<const float4*>(h + p0 * 80);
    float4* dst = reinterpret_cast<float4*>(hs);
    for (int i = threadIdx.x; i < 800; i += 320) dst[i] = src[i];
  }
  __syncthreads();
  int tid = threadIdx.x;
  int c2 = tid % 160;
  int grp = tid / 160;  // 0..1
  const float* W = (c2 < 80) ? Wk : Wv;
  float* outp = (c2 < 80) ? kb : vb;
  int c = (c2 < 80) ? c2 : (c2 - 80);
  float acc[5][4] = {};
  #pragma unroll
  for (int kh = 0; kh < 2; ++kh) {
    float wcol[40];
    #pragma unroll
    for (int kk = 0; kk < 40; ++kk) wcol[kk] = W[(kh * 40 + kk) * 80 + c];
    #pragma unroll
    for (int tt = 0; tt < 5; ++tt) {
      int t = grp + 2 * tt;
      dot4x40(hs + t * 320 + kh * 40, 80, wcol, acc[tt]);
    }
  }
  #pragma unroll
  for (int tt = 0; tt < 5; ++tt) {
    int t = grp + 2 * tt;
    #pragma unroll
    for (int j = 0; j < 4; ++j) outp[(p0 + t * 4 + j) * 80 + c] = acc[tt][j];
  }
}

// ---------------- Fused: q GEMM + neighbor attention + Wo (in-place) + FFN (half-tiles) ----------------
__global__ __launch_bounds__(320, 5) void battn_kernel(const float* __restrict__ h, const float* __restrict__ kb,
                                                       const float* __restrict__ vb, const int* __restrict__ nbr,
                                                       const float* __restrict__ Wq, const float* __restrict__ Wo,
                                                       const float* __restrict__ bo, const float* __restrict__ W1,
                                                       const float* __restrict__ b1, const float* __restrict__ W2,
                                                       const float* __restrict__ b2, float* __restrict__ hout) {
  __shared__ __align__(16) float hs[3200];       // h tile, becomes h2 in place (stride 80)
  __shared__ __align__(16) float qa[40 * 84];    // q then attn (stride 84: bank-conflict-free in attention)
  __shared__ __align__(16) float ts[20 * 160];   // FFN hidden, half the points at a time
  int b = blockIdx.x;
  int xcd = b & 7;
  int r = b >> 3;
  int graph = (xcd << 5) + (r / 25);
  int jb = r % 25;
  size_t gbase = (size_t)graph * 1000;
  size_t pbase = gbase + (size_t)jb * 40;
  int tid = threadIdx.x;
  {
    const float4* src = reinterpret_cast<const float4*>(h + pbase * 80);
    float4* dst = reinterpret_cast<float4*>(hs);
    for (int i = tid; i < 800; i += 320) dst[i] = src[i];
  }
  __syncthreads();
  int c = tid % 80, grp = tid / 80;  // 0..3 (q, Wo, FFN2 mapping)
  // ---- q = h @ Wq ----
  {
    float acc[3][4] = {};
    #pragma unroll
    for (int kh = 0; kh < 2; ++kh) {
      float wcol[40];
      #pragma unroll
      for (int kk = 0; kk < 40; ++kk) wcol[kk] = Wq[(kh * 40 + kk) * 80 + c];
      #pragma unroll
      for (int tt = 0; tt < 3; ++tt) {
        int t = grp + 4 * tt;
        if (t < 10) dot4x40(hs + t * 320 + kh * 40, 80, wcol, acc[tt]);
      }
    }
    #pragma unroll
    for (int tt = 0; tt < 3; ++tt) {
      int t = grp + 4 * tt;
      if (t < 10) {
        #pragma unroll
        for (int j = 0; j < 4; ++j) qa[(t * 4 + j) * 84 + c] = acc[tt][j];
      }
    }
  }
  __syncthreads();
  // ---- attention: thread = (point, head) ----
  {
    int p = tid >> 3, hh = tid & 7;
    int n = jb * 40 + p;
    float qv[10];
    #pragma unroll
    for (int d = 0; d < 10; ++d) qv[d] = qa[p * 84 + hh * 10 + d];
    int nb[8];
    #pragma unroll
    for (int kk = 0; kk < 8; ++kk) nb[kk] = nbr[(gbase + n) * 8 + kk];
    float sv[8];
    float denom = 0.f;
    #pragma unroll
    for (int kk = 0; kk < 8; ++kk) {
      const float2* kr = reinterpret_cast<const float2*>(kb + (gbase + nb[kk]) * 80 + hh * 10);
      float acc = 0.f;
      #pragma unroll
      for (int d2 = 0; d2 < 5; ++d2) {
        float2 kv2 = kr[d2];
        acc = fmaf(qv[2 * d2], kv2.x, acc);
        acc = fmaf(qv[2 * d2 + 1], kv2.y, acc);
      }
      float s = acc * 0.31622776601683794f;
      s = fminf(fmaxf(s, -5.f), 5.f);
      s = expf(s);
      sv[kk] = s;
      denom += s;
    }
    float wV[10] = {0, 0, 0, 0, 0, 0, 0, 0, 0, 0};
    #pragma unroll
    for (int kk = 0; kk < 8; ++kk) {
      const float2* vr = reinterpret_cast<const float2*>(vb + (gbase + nb[kk]) * 80 + hh * 10);
      #pragma unroll
      for (int d2 = 0; d2 < 5; ++d2) {
        float2 vv = vr[d2];
        wV[2 * d2] = fmaf(sv[kk], vv.x, wV[2 * d2]);
        wV[2 * d2 + 1] = fmaf(sv[kk], vv.y, wV[2 * d2 + 1]);
      }
    }
    float dn = denom + 1e-6f;
    #pragma unroll
    for (int d = 0; d < 10; ++d) qa[p * 84 + hh * 10 + d] = wV[d] / dn;
  }
  __syncthreads();
  // ---- hs = hs + attn @ Wo + bo (in place: each element touched only by its owner) ----
  {
    float acc[3][4] = {};
    #pragma unroll
    for (int kh = 0; kh < 2; ++kh) {
      float wcol[40];
      #pragma unroll
      for (int kk = 0; kk < 40; ++kk) wcol[kk] = Wo[(kh * 40 + kk) * 80 + c];
      #pragma unroll
      for (int tt = 0; tt < 3; ++tt) {
        int t = grp + 4 * tt;
        if (t < 10) dot4x40(qa + t * 336 + kh * 40, 84, wcol, acc[tt]);
      }
    }
    float bias = bo[c];
    #pragma unroll
    for (int tt = 0; tt < 3; ++tt) {
      int t = grp + 4 * tt;
      if (t < 10) {
        #pragma unroll
        for (int j = 0; j < 4; ++j) {
          int rr = t * 4 + j;
          hs[rr * 80 + c] = hs[rr * 80 + c] + acc[tt][j] + bias;
        }
      }
    }
  }
  __syncthreads();
  // ---- FFN in two 20-point halves ----
  #pragma unroll
  for (int half = 0; half < 2; ++half) {
    {  // ts = relu(h2 @ W1 + b1)
      int c1 = tid % 160, g1 = tid / 160;  // 0..1
      float acc[3][4] = {};
      #pragma unroll
      for (int kh = 0; kh < 2; ++kh) {
        float wcol[40];
        #pragma unroll
        for (int kk = 0; kk < 40; ++kk) wcol[kk] = W1[(kh * 40 + kk) * 160 + c1];
        #pragma unroll
        for (int tt = 0; tt < 3; ++tt) {
          int t = g1 + 2 * tt;
          if (t < 5) dot4x40(hs + (half * 20 + t * 4) * 80 + kh * 40, 80, wcol, acc[tt]);
        }
      }
      float bias = b1[c1];
      #pragma unroll
      for (int tt = 0; tt < 3; ++tt) {
        int t = g1 + 2 * tt;
        if (t < 5) {
          #pragma unroll
          for (int j = 0; j < 4; ++j) ts[(t * 4 + j) * 160 + c1] = fmaxf(acc[tt][j] + bias, 0.f);
        }
      }
    }
    __syncthreads();
    {  // hout = h2 + ts @ W2 + b2
      float acc[2][4] = {};
      #pragma unroll
      for (int kh = 0; kh < 4; ++kh) {
        float wcol[40];
        #pragma unroll
        for (int kk = 0; kk < 40; ++kk) wcol[kk] = W2[(kh * 40 + kk) * 80 + c];
        #pragma unroll
        for (int tt = 0; tt < 2; ++tt) {
          int t = grp + 4 * tt;
          if (t < 5) dot4x40(ts + t * 640 + kh * 40, 160, wcol, acc[tt]);
        }
      }
      float bias = b2[c];
      #pragma unroll
      for (int tt = 0; tt < 2; ++tt) {
        int t = grp + 4 * tt;
        if (t < 5) {
          #pragma unroll
          for (int j = 0; j < 4; ++j) {
            int rr = half * 20 + t * 4 + j;
            hout[(pbase + rr) * 80 + c] = hs[rr * 80 + c] + acc[tt][j] + bias;
          }
        }
      }
    }
    __syncthreads();
  }
}

// ---------------- Readout MLP 80->40->20->64->{3,1} ----------------
__global__ __launch_bounds__(320) void readout_kernel(const float* __restrict__ h, const float* __restrict__ Wr0,
                                                      const float* __restrict__ br0, const float* __restrict__ Wr1,
                                                      const float* __restrict__ br1, const float* __restrict__ Wr2,
                                                      const float* __restrict__ br2, const float* __restrict__ Wc,
                                                      const float* __restrict__ Wb, const float* __restrict__ bb,
                                                      float* __restrict__ out) {
  __shared__ __align__(16) float hs[3200];
  __shared__ __align__(16) float y0s[40 * 40];
  __shared__ __align__(16) float y1s[40 * 20];
  __shared__ __align__(16) float y2s[40 * 64];
  size_t p0 = (size_t)blockIdx.x * 40;
  int tid = threadIdx.x;
  {
    const float4* src = reinterpret_cast<const float4*>(h + p0 * 80);
    float4* dst = reinterpret_cast<float4*>(hs);
    for (int i = tid; i < 800; i += 320) dst[i] = src[i];
  }
  __syncthreads();
  {  // y0 = relu(h@Wr0 + br0)
    int c = tid % 40, grp = tid / 40;  // 0..7
    if (grp < 5) {
      float acc[8] = {};
      #pragma unroll
      for (int kh = 0; kh < 2; ++kh) {
        float wcol[40];
        #pragma unroll
        for (int kk = 0; kk < 40; ++kk) wcol[kk] = Wr0[(kh * 40 + kk) * 40 + c];
        #pragma unroll
        for (int j = 0; j < 8; ++j) {
          const float4* r4 = reinterpret_cast<const float4*>(hs + (grp * 8 + j) * 80 + kh * 40);
          #pragma unroll
          for (int kq = 0; kq < 10; ++kq) {
            float4 hv = r4[kq];
            acc[j] = fmaf(hv.x, wcol[4 * kq + 0], acc[j]);
            acc[j] = fmaf(hv.y, wcol[4 * kq + 1], acc[j]);
            acc[j] = fmaf(hv.z, wcol[4 * kq + 2], acc[j]);
            acc[j] = fmaf(hv.w, wcol[4 * kq + 3], acc[j]);
          }
        }
      }
      float bias = br0[c];
      #pragma unroll
      for (int j = 0; j < 8; ++j) y0s[(grp * 8 + j) * 40 + c] = fmaxf(acc[j] + bias, 0.f);
    }
  }
  __syncthreads();
  {  // y1 = relu(y0@Wr1 + br1)
    int c = tid % 20, grp = tid / 20;  // 0..15
    if (grp < 5) {
      float wcol[40];
      #pragma unroll
      for (int kk = 0; kk < 40; ++kk) wcol[kk] = Wr1[kk * 20 + c];
      float bias = br1[c];
      float acc[8] = {};
      #pragma unroll
      for (int j = 0; j < 8; ++j) {
        const float4* r4 = reinterpret_cast<const float4*>(y0s + (grp * 8 + j) * 40);
        #pragma unroll
        for (int kq = 0; kq < 10; ++kq) {
          float4 hv = r4[kq];
          acc[j] = fmaf(hv.x, wcol[4 * kq + 0], acc[j]);
          acc[j] = fmaf(hv.y, wcol[4 * kq + 1], acc[j]);
          acc[j] = fmaf(hv.z, wcol[4 * kq + 2], acc[j]);
          acc[j] = fmaf(hv.w, wcol[4 * kq + 3], acc[j]);
        }
      }
      #pragma unroll
      for (int j = 0; j < 8; ++j) y1s[(grp * 8 + j) * 20 + c] = fmaxf(acc[j] + bias, 0.f);
    }
  }
  __syncthreads();
  {  // y2 = y1@Wr2 + br2
    int c = tid % 64, grp = tid / 64;  // 0..4
    float wcol[20];
    #pragma unroll
    for (int kk = 0; kk < 20; ++kk) wcol[kk] = Wr2[kk * 64 + c];
    float bias = br2[c];
    float acc[8] = {};
    #pragma unroll
    for (int j = 0; j < 8; ++j) {
      const float4* r4 = reinterpret_cast<const float4*>(y1s + (grp * 8 + j) * 20);
      #pragma unroll
      for (int kq = 0; kq < 5; ++kq) {
        float4 hv = r4[kq];
        acc[j] = fmaf(hv.x, wcol[4 * kq + 0], acc[j]);
        acc[j] = fmaf(hv.y, wcol[4 * kq + 1], acc[j]);
        acc[j] = fmaf(hv.z, wcol[4 * kq + 2], acc[j]);
        acc[j] = fmaf(hv.w, wcol[4 * kq + 3], acc[j]);
      }
    }
    #pragma unroll
    for (int j = 0; j < 8; ++j) y2s[(grp * 8 + j) * 64 + c] = acc[j] + bias;
  }
  __syncthreads();
  {  // out: cc = y2@Wc, beta = y2@Wb + bb
    int c = tid % 4, p = tid / 4;
    if (p < 40) {
      float wcol[64];
      if (c < 3) {
        #pragma unroll
        for (int kk = 0; kk < 64; ++kk) wcol[kk] = Wc[kk * 3 + c];
      } else {
        #pragma unroll
        for (int kk = 0; kk < 64; ++kk) wcol[kk] = Wb[kk];
      }
      float acc = 0.f;
      #pragma unroll
      for (int kk = 0; kk < 64; ++kk) acc = fmaf(y2s[p * 64 + kk], wcol[kk], acc);
      if (c == 3) acc += bb[0];
      out[(p0 + p) * 4 + c] = acc;
    }
  }
}

extern "C" void kernel_launch(void* const* d_in, const int* in_sizes, int n_in,
                              void* d_out, int out_size, void* d_ws, size_t ws_size,
                              hipStream_t stream) {
  const float* hf = (const float*)d_in[0];
  const float* gamma = (const float*)d_in[1];
  const float* beta = (const float*)d_in[2];
  const float* We = (const float*)d_in[3];
  const float* be = (const float*)d_in[4];
  const float* Wq = (const float*)d_in[5];
  const float* Wk = (const float*)d_in[6];
  const float* Wv = (const float*)d_in[7];
  const float* Wo = (const float*)d_in[8];
  const float* bo = (const float*)d_in[9];
  const float* W1 = (const float*)d_in[10];
  const float* b1 = (const float*)d_in[11];
  const float* W2 = (const float*)d_in[12];
  const float* b2 = (const float*)d_in[13];
  const float* Wr0 = (const float*)d_in[14];
  const float* br0 = (const float*)d_in[15];
  const float* Wr1 = (const float*)d_in[16];
  const float* br1 = (const float*)d_in[17];
  const float* Wr2 = (const float*)d_in[18];
  const float* br2 = (const float*)d_in[19];
  const float* Wc = (const float*)d_in[20];
  const float* Wb = (const float*)d_in[21];
  const float* bb = (const float*)d_in[22];
  float* out = (float*)d_out;

  char* wsp = (char*)d_ws;
  int* nbr = (int*)wsp;            wsp += (size_t)256000 * 8 * 4;
  float* hA = (float*)wsp;         wsp += (size_t)256000 * 80 * 4;
  float* kbuf = (float*)wsp;       wsp += (size_t)256000 * 80 * 4;
  float* vbuf = (float*)wsp;       wsp += (size_t)256000 * 80 * 4;
  float* partial = (float*)wsp;    wsp += (size_t)1000 * 18 * 4;
  float* stats = (float*)wsp;      wsp += 18 * 4;

  knn_kernel<<<1024, 256, 0, stream>>>(hf, nbr);
  bn_stat1<<<1000, 256, 0, stream>>>(hf, partial);
  bn_stat2<<<1, 256, 0, stream>>>(partial, stats);
  embed_kernel<<<6400, 320, 0, stream>>>(hf, stats, gamma, beta, We, be, hA);
  for (int l = 0; l < 10; ++l) {
    kv_kernel<<<6400, 320, 0, stream>>>(hA, Wk + (size_t)l * 6400, Wv + (size_t)l * 6400, kbuf, vbuf);
    battn_kernel<<<6400, 320, 0, stream>>>(hA, kbuf, vbuf, nbr,
                                           Wq + (size_t)l * 6400, Wo + (size_t)l * 6400, bo + (size_t)l * 80,
                                           W1 + (size_t)l * 12800, b1 + (size_t)l * 160,
                                           W2 + (size_t)l * 12800, b2 + (size_t)l * 80, hA);
  }
  readout_kernel<<<6400, 320, 0, stream>>>(hA, Wr0, br0, Wr1, br1, Wr2, br2, Wc, Wb, bb, out);
}

// Round 4
// 9739.330 us; speedup vs baseline: 5.3397x; 5.3397x over previous
//
#include <hip/hip_runtime.h>
#include <cstdint>
#include <cstddef>

// G=256 graphs, NP=1000 points, K=8 neighbors, H=8 heads, DH=10, D=80, NL=10 layers

// ---------------- KNN: exact reference-order arithmetic, stable tie-break ----------------
__global__ __launch_bounds__(256) void knn_kernel(const float* __restrict__ hf, int* __restrict__ nbr) {
  __shared__ float cs[3000];
  int b = blockIdx.x;
  int g = b >> 2;
  int q = b & 3;
  for (int i = threadIdx.x; i < 3000; i += 256) {
    cs[i] = hf[((size_t)g * 1000 + (i / 3)) * 9 + (i % 3)];
  }
  __syncthreads();
  int tid = threadIdx.x;
  if (tid < 250) {
    int n = q * 250 + tid;
    float cx = cs[n * 3 + 0], cy = cs[n * 3 + 1], cz = cs[n * 3 + 2];
    float bd[8];
    int bi[8];
    #pragma unroll
    for (int q2 = 0; q2 < 8; ++q2) { bd[q2] = 3.402823466e38f; bi[q2] = 0; }
    for (int j = 0; j < 1000; ++j) {
      float dx = __fsub_rn(cx, cs[j * 3 + 0]);
      float dy = __fsub_rn(cy, cs[j * 3 + 1]);
      float dz = __fsub_rn(cz, cs[j * 3 + 2]);
      float d2 = __fadd_rn(__fadd_rn(__fmul_rn(dx, dx), __fmul_rn(dy, dy)), __fmul_rn(dz, dz));
      if (d2 < bd[7]) {
        bd[7] = d2; bi[7] = j;
        #pragma unroll
        for (int q2 = 7; q2 >= 1; --q2) {
          if (bd[q2] < bd[q2 - 1]) {
            float tf = bd[q2]; bd[q2] = bd[q2 - 1]; bd[q2 - 1] = tf;
            int ti = bi[q2]; bi[q2] = bi[q2 - 1]; bi[q2 - 1] = ti;
          }
        }
      }
    }
    #pragma unroll
    for (int kk = 0; kk < 8; ++kk) nbr[((size_t)g * 1000 + n) * 8 + kk] = bi[kk];
  }
}

// ---------------- BatchNorm stats (deterministic two-stage) ----------------
__global__ __launch_bounds__(256) void bn_stat1(const float* __restrict__ hf, float* __restrict__ partial) {
  __shared__ float red[4][18];
  int row = blockIdx.x * 256 + threadIdx.x;
  float s[9], ss[9];
  #pragma unroll
  for (int f = 0; f < 9; ++f) {
    float v = hf[(size_t)row * 9 + f];
    s[f] = v;
    ss[f] = v * v;
  }
  for (int off = 32; off > 0; off >>= 1) {
    #pragma unroll
    for (int f = 0; f < 9; ++f) {
      s[f] += __shfl_down(s[f], off);
      ss[f] += __shfl_down(ss[f], off);
    }
  }
  int wid = threadIdx.x >> 6, lane = threadIdx.x & 63;
  if (lane == 0) {
    #pragma unroll
    for (int f = 0; f < 9; ++f) { red[wid][f] = s[f]; red[wid][9 + f] = ss[f]; }
  }
  __syncthreads();
  if (threadIdx.x < 18) {
    partial[(size_t)blockIdx.x * 18 + threadIdx.x] =
        red[0][threadIdx.x] + red[1][threadIdx.x] + red[2][threadIdx.x] + red[3][threadIdx.x];
  }
}

__global__ __launch_bounds__(256) void bn_stat2(const float* __restrict__ partial, float* __restrict__ stats) {
  __shared__ double sd[9][28], qd[9][28];
  int tid = threadIdx.x;
  if (tid < 252) {
    int f = tid % 9, gq = tid / 9;
    double s = 0.0, q = 0.0;
    for (int b = gq; b < 1000; b += 28) {
      s += (double)partial[b * 18 + f];
      q += (double)partial[b * 18 + 9 + f];
    }
    sd[f][gq] = s;
    qd[f][gq] = q;
  }
  __syncthreads();
  if (tid < 9) {
    double s = 0.0, q = 0.0;
    for (int g2 = 0; g2 < 28; ++g2) { s += sd[tid][g2]; q += qd[tid][g2]; }
    double mu = s / 256000.0;
    double var = q / 256000.0 - mu * mu;
    stats[tid] = (float)mu;
    stats[9 + tid] = (float)(1.0 / sqrt(var + 1e-5));
  }
}

// ---------------- Weight transpose: W[R][C] -> WT[C][R], one block per matrix ----------------
__global__ __launch_bounds__(256) void transpose_k(const float* __restrict__ src, float* __restrict__ dst,
                                                   int R, int C) {
  const float* s = src + (size_t)blockIdx.x * R * C;
  float* d = dst + (size_t)blockIdx.x * R * C;
  int n = R * C;
  for (int i = threadIdx.x; i < n; i += 256) {
    int rr = i / C, cc = i % C;
    d[cc * R + rr] = s[i];
  }
}

// ---------------- Embed: normalize + (9->80) ----------------
__global__ __launch_bounds__(320) void embed_kernel(const float* __restrict__ hf, const float* __restrict__ stats,
                                                    const float* __restrict__ gamma, const float* __restrict__ beta,
                                                    const float* __restrict__ We, const float* __restrict__ be,
                                                    float* __restrict__ h) {
  __shared__ __align__(16) float xs[40 * 9];
  size_t p0 = (size_t)blockIdx.x * 40;
  for (int i = threadIdx.x; i < 360; i += 320) {
    int f = i % 9;
    float x = hf[p0 * 9 + i];
    xs[i] = (x - stats[f]) * stats[9 + f] * gamma[f] + beta[f];
  }
  __syncthreads();
  int c = threadIdx.x % 80, pg = threadIdx.x / 80;
  float we[9];
  #pragma unroll
  for (int f = 0; f < 9; ++f) we[f] = We[f * 80 + c];
  float bias = be[c];
  for (int pp = 0; pp < 10; ++pp) {
    int p = pg * 10 + pp;
    float acc = 0.f;
    #pragma unroll
    for (int f = 0; f < 9; ++f) acc = fmaf(xs[p * 9 + f], we[f], acc);
    h[(p0 + p) * 80 + c] = acc + bias;
  }
}

// ---------------- K,V projection (r1-proven structure: full wcol, scalar weight loads) ----------------
__global__ __launch_bounds__(320) void kv_kernel(const float* __restrict__ h, const float* __restrict__ Wk,
                                                 const float* __restrict__ Wv, float* __restrict__ kb,
                                                 float* __restrict__ vb) {
  __shared__ __align__(16) float hs[40 * 80];
  size_t p0 = (size_t)blockIdx.x * 40;
  {
    const float4* src = reinterpret_cast<const float4*>(h + p0 * 80);
    float4* dst = reinterpret_cast<float4*>(hs);
    for (int i = threadIdx.x; i < 800; i += 320) dst[i] = src[i];
  }
  __syncthreads();
  int tid = threadIdx.x;
  int c2 = tid % 160;
  int grp = tid / 160;  // 0..1
  const float* W = (c2 < 80) ? Wk : Wv;
  float* outp = (c2 < 80) ? kb : vb;
  int c = (c2 < 80) ? c2 : (c2 - 80);
  float wcol[80];
  #pragma unroll
  for (int kk = 0; kk < 80; ++kk) wcol[kk] = W[kk * 80 + c];
  // 5 tiles of 8 rows; grp0: t=0,2,4  grp1: t=1,3
  #pragma unroll
  for (int tt = 0; tt < 3; ++tt) {
    int t = grp + 2 * tt;
    if (t < 5) {
      float acc[8] = {};
      #pragma unroll
      for (int j = 0; j < 8; ++j) {
        const float4* r4 = reinterpret_cast<const float4*>(hs + (t * 8 + j) * 80);
        #pragma unroll
        for (int kq = 0; kq < 20; ++kq) {
          float4 hv = r4[kq];
          acc[j] = fmaf(hv.x, wcol[4 * kq + 0], acc[j]);
          acc[j] = fmaf(hv.y, wcol[4 * kq + 1], acc[j]);
          acc[j] = fmaf(hv.z, wcol[4 * kq + 2], acc[j]);
          acc[j] = fmaf(hv.w, wcol[4 * kq + 3], acc[j]);
        }
      }
      #pragma unroll
      for (int j = 0; j < 8; ++j) outp[(p0 + t * 8 + j) * 80 + c] = acc[j];
    }
  }
}

// ---------------- Fused: q GEMM + attention + Wo (in-place) + FFN, 2 cols/thread, transposed weights --------
__global__ __launch_bounds__(320) void battn_kernel(const float* __restrict__ h, const float* __restrict__ kb,
                                                    const float* __restrict__ vb, const int* __restrict__ nbr,
                                                    const float* __restrict__ WqT, const float* __restrict__ WoT,
                                                    const float* __restrict__ bo, const float* __restrict__ W1T,
                                                    const float* __restrict__ b1, const float* __restrict__ W2T,
                                                    const float* __restrict__ b2, float* __restrict__ hout) {
  __shared__ __align__(16) float hs[40 * 84];   // h tile, becomes h+attn@Wo in place (stride 84)
  __shared__ __align__(16) float qa[40 * 84];   // q, then attn (stride 84)
  __shared__ __align__(16) float ts[40 * 164];  // relu FFN hidden (stride 164)
  int b = blockIdx.x;
  int xcd = b & 7;
  int r = b >> 3;
  int graph = (xcd << 5) + (r / 25);
  int jb = r % 25;
  size_t gbase = (size_t)graph * 1000;
  size_t pbase = gbase + (size_t)jb * 40;
  int tid = threadIdx.x;
  // stage h tile into hs (stride 84)
  for (int i = tid; i < 800; i += 320) {
    int row = i / 20, kq = i % 20;
    float4 v = reinterpret_cast<const float4*>(h + (pbase + row) * 80)[kq];
    *reinterpret_cast<float4*>(&hs[row * 84 + kq * 4]) = v;
  }
  __syncthreads();
  // ---- q = h @ Wq : 40 colpairs x 8 rowgroups of 5 ----
  {
    int c2 = tid % 40, g = tid / 40;
    float acc0[5] = {}, acc1[5] = {};
    #pragma unroll
    for (int kc = 0; kc < 4; ++kc) {
      float w0[20], w1[20];
      const float4* wp0 = reinterpret_cast<const float4*>(WqT + c2 * 80 + kc * 20);
      const float4* wp1 = reinterpret_cast<const float4*>(WqT + (c2 + 40) * 80 + kc * 20);
      #pragma unroll
      for (int q5 = 0; q5 < 5; ++q5) {
        float4 a = wp0[q5];
        w0[4 * q5 + 0] = a.x; w0[4 * q5 + 1] = a.y; w0[4 * q5 + 2] = a.z; w0[4 * q5 + 3] = a.w;
        float4 bb2 = wp1[q5];
        w1[4 * q5 + 0] = bb2.x; w1[4 * q5 + 1] = bb2.y; w1[4 * q5 + 2] = bb2.z; w1[4 * q5 + 3] = bb2.w;
      }
      #pragma unroll
      for (int rr = 0; rr < 5; ++rr) {
        const float4* hp = reinterpret_cast<const float4*>(&hs[(g * 5 + rr) * 84 + kc * 20]);
        #pragma unroll
        for (int q5 = 0; q5 < 5; ++q5) {
          float4 hv = hp[q5];
          acc0[rr] = fmaf(hv.x, w0[4 * q5 + 0], acc0[rr]);
          acc0[rr] = fmaf(hv.y, w0[4 * q5 + 1], acc0[rr]);
          acc0[rr] = fmaf(hv.z, w0[4 * q5 + 2], acc0[rr]);
          acc0[rr] = fmaf(hv.w, w0[4 * q5 + 3], acc0[rr]);
          acc1[rr] = fmaf(hv.x, w1[4 * q5 + 0], acc1[rr]);
          acc1[rr] = fmaf(hv.y, w1[4 * q5 + 1], acc1[rr]);
          acc1[rr] = fmaf(hv.z, w1[4 * q5 + 2], acc1[rr]);
          acc1[rr] = fmaf(hv.w, w1[4 * q5 + 3], acc1[rr]);
        }
      }
    }
    #pragma unroll
    for (int rr = 0; rr < 5; ++rr) {
      int row = g * 5 + rr;
      qa[row * 84 + c2] = acc0[rr];
      qa[row * 84 + c2 + 40] = acc1[rr];
    }
  }
  __syncthreads();
  // ---- attention: thread = (point, head) ----
  {
    int p = tid >> 3, hh = tid & 7;
    int n = jb * 40 + p;
    float qv[10];
    #pragma unroll
    for (int d = 0; d < 10; ++d) qv[d] = qa[p * 84 + hh * 10 + d];
    int nb[8];
    #pragma unroll
    for (int kk = 0; kk < 8; ++kk) nb[kk] = nbr[(gbase + n) * 8 + kk];
    float sv[8];
    float denom = 0.f;
    #pragma unroll
    for (int kk = 0; kk < 8; ++kk) {
      const float2* kr = reinterpret_cast<const float2*>(kb + (gbase + nb[kk]) * 80 + hh * 10);
      float acc = 0.f;
      #pragma unroll
      for (int d2 = 0; d2 < 5; ++d2) {
        float2 kv2 = kr[d2];
        acc = fmaf(qv[2 * d2], kv2.x, acc);
        acc = fmaf(qv[2 * d2 + 1], kv2.y, acc);
      }
      float s = acc * 0.31622776601683794f;
      s = fminf(fmaxf(s, -5.f), 5.f);
      s = expf(s);
      sv[kk] = s;
      denom += s;
    }
    float wV[10] = {0, 0, 0, 0, 0, 0, 0, 0, 0, 0};
    #pragma unroll
    for (int kk = 0; kk < 8; ++kk) {
      const float2* vr = reinterpret_cast<const float2*>(vb + (gbase + nb[kk]) * 80 + hh * 10);
      #pragma unroll
      for (int d2 = 0; d2 < 5; ++d2) {
        float2 vv = vr[d2];
        wV[2 * d2] = fmaf(sv[kk], vv.x, wV[2 * d2]);
        wV[2 * d2 + 1] = fmaf(sv[kk], vv.y, wV[2 * d2 + 1]);
      }
    }
    float dn = denom + 1e-6f;
    #pragma unroll
    for (int d = 0; d < 10; ++d) qa[p * 84 + hh * 10 + d] = wV[d] / dn;
  }
  __syncthreads();
  // ---- hs += attn @ Wo + bo (in place) ----
  {
    int c2 = tid % 40, g = tid / 40;
    float acc0[5] = {}, acc1[5] = {};
    #pragma unroll
    for (int kc = 0; kc < 4; ++kc) {
      float w0[20], w1[20];
      const float4* wp0 = reinterpret_cast<const float4*>(WoT + c2 * 80 + kc * 20);
      const float4* wp1 = reinterpret_cast<const float4*>(WoT + (c2 + 40) * 80 + kc * 20);
      #pragma unroll
      for (int q5 = 0; q5 < 5; ++q5) {
        float4 a = wp0[q5];
        w0[4 * q5 + 0] = a.x; w0[4 * q5 + 1] = a.y; w0[4 * q5 + 2] = a.z; w0[4 * q5 + 3] = a.w;
        float4 bb2 = wp1[q5];
        w1[4 * q5 + 0] = bb2.x; w1[4 * q5 + 1] = bb2.y; w1[4 * q5 + 2] = bb2.z; w1[4 * q5 + 3] = bb2.w;
      }
      #pragma unroll
      for (int rr = 0; rr < 5; ++rr) {
        const float4* hp = reinterpret_cast<const float4*>(&qa[(g * 5 + rr) * 84 + kc * 20]);
        #pragma unroll
        for (int q5 = 0; q5 < 5; ++q5) {
          float4 hv = hp[q5];
          acc0[rr] = fmaf(hv.x, w0[4 * q5 + 0], acc0[rr]);
          acc0[rr] = fmaf(hv.y, w0[4 * q5 + 1], acc0[rr]);
          acc0[rr] = fmaf(hv.z, w0[4 * q5 + 2], acc0[rr]);
          acc0[rr] = fmaf(hv.w, w0[4 * q5 + 3], acc0[rr]);
          acc1[rr] = fmaf(hv.x, w1[4 * q5 + 0], acc1[rr]);
          acc1[rr] = fmaf(hv.y, w1[4 * q5 + 1], acc1[rr]);
          acc1[rr] = fmaf(hv.z, w1[4 * q5 + 2], acc1[rr]);
          acc1[rr] = fmaf(hv.w, w1[4 * q5 + 3], acc1[rr]);
        }
      }
    }
    float bias0 = bo[c2], bias1 = bo[c2 + 40];
    #pragma unroll
    for (int rr = 0; rr < 5; ++rr) {
      int row = g * 5 + rr;
      hs[row * 84 + c2] += acc0[rr] + bias0;
      hs[row * 84 + c2 + 40] += acc1[rr] + bias1;
    }
  }
  __syncthreads();
  // ---- ts = relu(h2 @ W1 + b1): 80 colpairs x 4 rowgroups of 10 ----
  {
    int c2 = tid % 80, g = tid / 80;
    float acc0[10] = {}, acc1[10] = {};
    #pragma unroll
    for (int kc = 0; kc < 4; ++kc) {
      float w0[20], w1[20];
      const float4* wp0 = reinterpret_cast<const float4*>(W1T + c2 * 80 + kc * 20);
      const float4* wp1 = reinterpret_cast<const float4*>(W1T + (c2 + 80) * 80 + kc * 20);
      #pragma unroll
      for (int q5 = 0; q5 < 5; ++q5) {
        float4 a = wp0[q5];
        w0[4 * q5 + 0] = a.x; w0[4 * q5 + 1] = a.y; w0[4 * q5 + 2] = a.z; w0[4 * q5 + 3] = a.w;
        float4 bb2 = wp1[q5];
        w1[4 * q5 + 0] = bb2.x; w1[4 * q5 + 1] = bb2.y; w1[4 * q5 + 2] = bb2.z; w1[4 * q5 + 3] = bb2.w;
      }
      #pragma unroll
      for (int rr = 0; rr < 10; ++rr) {
        const float4* hp = reinterpret_cast<const float4*>(&hs[(g * 10 + rr) * 84 + kc * 20]);
        #pragma unroll
        for (int q5 = 0; q5 < 5; ++q5) {
          float4 hv = hp[q5];
          acc0[rr] = fmaf(hv.x, w0[4 * q5 + 0], acc0[rr]);
          acc0[rr] = fmaf(hv.y, w0[4 * q5 + 1], acc0[rr]);
          acc0[rr] = fmaf(hv.z, w0[4 * q5 + 2], acc0[rr]);
          acc0[rr] = fmaf(hv.w, w0[4 * q5 + 3], acc0[rr]);
          acc1[rr] = fmaf(hv.x, w1[4 * q5 + 0], acc1[rr]);
          acc1[rr] = fmaf(hv.y, w1[4 * q5 + 1], acc1[rr]);
          acc1[rr] = fmaf(hv.z, w1[4 * q5 + 2], acc1[rr]);
          acc1[rr] = fmaf(hv.w, w1[4 * q5 + 3], acc1[rr]);
        }
      }
    }
    float bias0 = b1[c2], bias1 = b1[c2 + 80];
    #pragma unroll
    for (int rr = 0; rr < 10; ++rr) {
      int row = g * 10 + rr;
      ts[row * 164 + c2] = fmaxf(acc0[rr] + bias0, 0.f);
      ts[row * 164 + c2 + 80] = fmaxf(acc1[rr] + bias1, 0.f);
    }
  }
  __syncthreads();
  // ---- hout = h2 + ts @ W2 + b2: 40 colpairs x 8 rowgroups of 5, K=160 ----
  {
    int c2 = tid % 40, g = tid / 40;
    float acc0[5] = {}, acc1[5] = {};
    #pragma unroll
    for (int kc = 0; kc < 8; ++kc) {
      float w0[20], w1[20];
      const float4* wp0 = reinterpret_cast<const float4*>(W2T + c2 * 160 + kc * 20);
      const float4* wp1 = reinterpret_cast<const float4*>(W2T + (c2 + 40) * 160 + kc * 20);
      #pragma unroll
      for (int q5 = 0; q5 < 5; ++q5) {
        float4 a = wp0[q5];
        w0[4 * q5 + 0] = a.x; w0[4 * q5 + 1] = a.y; w0[4 * q5 + 2] = a.z; w0[4 * q5 + 3] = a.w;
        float4 bb2 = wp1[q5];
        w1[4 * q5 + 0] = bb2.x; w1[4 * q5 + 1] = bb2.y; w1[4 * q5 + 2] = bb2.z; w1[4 * q5 + 3] = bb2.w;
      }
      #pragma unroll
      for (int rr = 0; rr < 5; ++rr) {
        const float4* hp = reinterpret_cast<const float4*>(&ts[(g * 5 + rr) * 164 + kc * 20]);
        #pragma unroll
        for (int q5 = 0; q5 < 5; ++q5) {
          float4 hv = hp[q5];
          acc0[rr] = fmaf(hv.x, w0[4 * q5 + 0], acc0[rr]);
          acc0[rr] = fmaf(hv.y, w0[4 * q5 + 1], acc0[rr]);
          acc0[rr] = fmaf(hv.z, w0[4 * q5 + 2], acc0[rr]);
          acc0[rr] = fmaf(hv.w, w0[4 * q5 + 3], acc0[rr]);
          acc1[rr] = fmaf(hv.x, w1[4 * q5 + 0], acc1[rr]);
          acc1[rr] = fmaf(hv.y, w1[4 * q5 + 1], acc1[rr]);
          acc1[rr] = fmaf(hv.z, w1[4 * q5 + 2], acc1[rr]);
          acc1[rr] = fmaf(hv.w, w1[4 * q5 + 3], acc1[rr]);
        }
      }
    }
    float bias0 = b2[c2], bias1 = b2[c2 + 40];
    #pragma unroll
    for (int rr = 0; rr < 5; ++rr) {
      int row = g * 5 + rr;
      hout[(pbase + row) * 80 + c2] = hs[row * 84 + c2] + acc0[rr] + bias0;
      hout[(pbase + row) * 80 + c2 + 40] = hs[row * 84 + c2 + 40] + acc1[rr] + bias1;
    }
  }
}

// ---------------- Readout MLP 80->40->20->64->{3,1} ----------------
__global__ __launch_bounds__(320) void readout_kernel(const float* __restrict__ h, const float* __restrict__ Wr0,
                                                      const float* __restrict__ br0, const float* __restrict__ Wr1,
                                                      const float* __restrict__ br1, const float* __restrict__ Wr2,
                                                      const float* __restrict__ br2, const float* __restrict__ Wc,
                                                      const float* __restrict__ Wb, const float* __restrict__ bb,
                                                      float* __restrict__ out) {
  __shared__ __align__(16) float hs[3200];
  __shared__ __align__(16) float y0s[40 * 40];
  __shared__ __align__(16) float y1s[40 * 20];
  __shared__ __align__(16) float y2s[40 * 64];
  size_t p0 = (size_t)blockIdx.x * 40;
  int tid = threadIdx.x;
  {
    const float4* src = reinterpret_cast<const float4*>(h + p0 * 80);
    float4* dst = reinterpret_cast<float4*>(hs);
    for (int i = tid; i < 800; i += 320) dst[i] = src[i];
  }
  __syncthreads();
  {  // y0 = relu(h@Wr0 + br0)
    int c = tid % 40, grp = tid / 40;  // 0..7
    if (grp < 5) {
      float wcol[80];
      #pragma unroll
      for (int kk = 0; kk < 80; ++kk) wcol[kk] = Wr0[kk * 40 + c];
      float bias = br0[c];
      float acc[8] = {};
      #pragma unroll
      for (int j = 0; j < 8; ++j) {
        const float4* r4 = reinterpret_cast<const float4*>(hs + (grp * 8 + j) * 80);
        #pragma unroll
        for (int kq = 0; kq < 20; ++kq) {
          float4 hv = r4[kq];
          acc[j] = fmaf(hv.x, wcol[4 * kq + 0], acc[j]);
          acc[j] = fmaf(hv.y, wcol[4 * kq + 1], acc[j]);
          acc[j] = fmaf(hv.z, wcol[4 * kq + 2], acc[j]);
          acc[j] = fmaf(hv.w, wcol[4 * kq + 3], acc[j]);
        }
      }
      #pragma unroll
      for (int j = 0; j < 8; ++j) y0s[(grp * 8 + j) * 40 + c] = fmaxf(acc[j] + bias, 0.f);
    }
  }
  __syncthreads();
  {  // y1 = relu(y0@Wr1 + br1)
    int c = tid % 20, grp = tid / 20;  // 0..15
    if (grp < 5) {
      float wcol[40];
      #pragma unroll
      for (int kk = 0; kk < 40; ++kk) wcol[kk] = Wr1[kk * 20 + c];
      float bias = br1[c];
      float acc[8] = {};
      #pragma unroll
      for (int j = 0; j < 8; ++j) {
        const float4* r4 = reinterpret_cast<const float4*>(y0s + (grp * 8 + j) * 40);
        #pragma unroll
        for (int kq = 0; kq < 10; ++kq) {
          float4 hv = r4[kq];
          acc[j] = fmaf(hv.x, wcol[4 * kq + 0], acc[j]);
          acc[j] = fmaf(hv.y, wcol[4 * kq + 1], acc[j]);
          acc[j] = fmaf(hv.z, wcol[4 * kq + 2], acc[j]);
          acc[j] = fmaf(hv.w, wcol[4 * kq + 3], acc[j]);
        }
      }
      #pragma unroll
      for (int j = 0; j < 8; ++j) y1s[(grp * 8 + j) * 20 + c] = fmaxf(acc[j] + bias, 0.f);
    }
  }
  __syncthreads();
  {  // y2 = y1@Wr2 + br2
    int c = tid % 64, grp = tid / 64;  // 0..4
    float wcol[20];
    #pragma unroll
    for (int kk = 0; kk < 20; ++kk) wcol[kk] = Wr2[kk * 64 + c];
    float bias = br2[c];
    float acc[8] = {};
    #pragma unroll
    for (int j = 0; j < 8; ++j) {
      const float4* r4 = reinterpret_cast<const float4*>(y1s + (grp * 8 + j) * 20);
      #pragma unroll
      for (int kq = 0; kq < 5; ++kq) {
        float4 hv = r4[kq];
        acc[j] = fmaf(hv.x, wcol[4 * kq + 0], acc[j]);
        acc[j] = fmaf(hv.y, wcol[4 * kq + 1], acc[j]);
        acc[j] = fmaf(hv.z, wcol[4 * kq + 2], acc[j]);
        acc[j] = fmaf(hv.w, wcol[4 * kq + 3], acc[j]);
      }
    }
    #pragma unroll
    for (int j = 0; j < 8; ++j) y2s[(grp * 8 + j) * 64 + c] = acc[j] + bias;
  }
  __syncthreads();
  {  // out: cc = y2@Wc, beta = y2@Wb + bb
    int c = tid % 4, p = tid / 4;
    if (p < 40) {
      float wcol[64];
      if (c < 3) {
        #pragma unroll
        for (int kk = 0; kk < 64; ++kk) wcol[kk] = Wc[kk * 3 + c];
      } else {
        #pragma unroll
        for (int kk = 0; kk < 64; ++kk) wcol[kk] = Wb[kk];
      }
      float acc = 0.f;
      #pragma unroll
      for (int kk = 0; kk < 64; ++kk) acc = fmaf(y2s[p * 64 + kk], wcol[kk], acc);
      if (c == 3) acc += bb[0];
      out[(p0 + p) * 4 + c] = acc;
    }
  }
}

extern "C" void kernel_launch(void* const* d_in, const int* in_sizes, int n_in,
                              void* d_out, int out_size, void* d_ws, size_t ws_size,
                              hipStream_t stream) {
  const float* hf = (const float*)d_in[0];
  const float* gamma = (const float*)d_in[1];
  const float* beta = (const float*)d_in[2];
  const float* We = (const float*)d_in[3];
  const float* be = (const float*)d_in[4];
  const float* Wq = (const float*)d_in[5];
  const float* Wk = (const float*)d_in[6];
  const float* Wv = (const float*)d_in[7];
  const float* Wo = (const float*)d_in[8];
  const float* bo = (const float*)d_in[9];
  const float* W1 = (const float*)d_in[10];
  const float* b1 = (const float*)d_in[11];
  const float* W2 = (const float*)d_in[12];
  const float* b2 = (const float*)d_in[13];
  const float* Wr0 = (const float*)d_in[14];
  const float* br0 = (const float*)d_in[15];
  const float* Wr1 = (const float*)d_in[16];
  const float* br1 = (const float*)d_in[17];
  const float* Wr2 = (const float*)d_in[18];
  const float* br2 = (const float*)d_in[19];
  const float* Wc = (const float*)d_in[20];
  const float* Wb = (const float*)d_in[21];
  const float* bb = (const float*)d_in[22];
  float* out = (float*)d_out;

  char* wsp = (char*)d_ws;
  int* nbr = (int*)wsp;            wsp += (size_t)256000 * 8 * 4;
  float* hA = (float*)wsp;         wsp += (size_t)256000 * 80 * 4;
  float* kbuf = (float*)wsp;       wsp += (size_t)256000 * 80 * 4;
  float* vbuf = (float*)wsp;       wsp += (size_t)256000 * 80 * 4;
  float* partial = (float*)wsp;    wsp += (size_t)1000 * 18 * 4;
  float* stats = (float*)wsp;      wsp += 128;  // 18 floats = 72 B; r3 bug was 64 B (overlapped WqT!)
  float* WqT = (float*)wsp;        wsp += (size_t)10 * 6400 * 4;
  float* WoT = (float*)wsp;        wsp += (size_t)10 * 6400 * 4;
  float* W1T = (float*)wsp;        wsp += (size_t)10 * 12800 * 4;
  float* W2T = (float*)wsp;        wsp += (size_t)10 * 12800 * 4;

  knn_kernel<<<1024, 256, 0, stream>>>(hf, nbr);
  bn_stat1<<<1000, 256, 0, stream>>>(hf, partial);
  bn_stat2<<<1, 256, 0, stream>>>(partial, stats);
  transpose_k<<<10, 256, 0, stream>>>(Wq, WqT, 80, 80);
  transpose_k<<<10, 256, 0, stream>>>(Wo, WoT, 80, 80);
  transpose_k<<<10, 256, 0, stream>>>(W1, W1T, 80, 160);
  transpose_k<<<10, 256, 0, stream>>>(W2, W2T, 160, 80);
  embed_kernel<<<6400, 320, 0, stream>>>(hf, stats, gamma, beta, We, be, hA);
  for (int l = 0; l < 10; ++l) {
    kv_kernel<<<6400, 320, 0, stream>>>(hA, Wk + (size_t)l * 6400, Wv + (size_t)l * 6400, kbuf, vbuf);
    battn_kernel<<<6400, 320, 0, stream>>>(hA, kbuf, vbuf, nbr,
                                           WqT + (size_t)l * 6400, WoT + (size_t)l * 6400, bo + (size_t)l * 80,
                                           W1T + (size_t)l * 12800, b1 + (size_t)l * 160,
                                           W2T + (size_t)l * 12800, b2 + (size_t)l * 80, hA);
  }
  readout_kernel<<<6400, 320, 0, stream>>>(hA, Wr0, br0, Wr1, br1, Wr2, br2, Wc, Wb, bb, out);
}

// Round 5
// 8906.473 us; speedup vs baseline: 5.8391x; 1.0935x over previous
//
#include <hip/hip_runtime.h>
#include <cstdint>
#include <cstddef>

// G=256 graphs, NP=1000 points, K=8 neighbors, H=8 heads, DH=10, D=80, NL=10 layers

// ---------------- KNN: exact reference-order arithmetic, stable tie-break ----------------
__global__ __launch_bounds__(256) void knn_kernel(const float* __restrict__ hf, int* __restrict__ nbr) {
  __shared__ float cs[3000];
  int b = blockIdx.x;
  int g = b >> 2;
  int q = b & 3;
  for (int i = threadIdx.x; i < 3000; i += 256) {
    cs[i] = hf[((size_t)g * 1000 + (i / 3)) * 9 + (i % 3)];
  }
  __syncthreads();
  int tid = threadIdx.x;
  if (tid < 250) {
    int n = q * 250 + tid;
    float cx = cs[n * 3 + 0], cy = cs[n * 3 + 1], cz = cs[n * 3 + 2];
    float bd[8];
    int bi[8];
    #pragma unroll
    for (int q2 = 0; q2 < 8; ++q2) { bd[q2] = 3.402823466e38f; bi[q2] = 0; }
    for (int j = 0; j < 1000; ++j) {
      float dx = __fsub_rn(cx, cs[j * 3 + 0]);
      float dy = __fsub_rn(cy, cs[j * 3 + 1]);
      float dz = __fsub_rn(cz, cs[j * 3 + 2]);
      float d2 = __fadd_rn(__fadd_rn(__fmul_rn(dx, dx), __fmul_rn(dy, dy)), __fmul_rn(dz, dz));
      if (d2 < bd[7]) {
        bd[7] = d2; bi[7] = j;
        #pragma unroll
        for (int q2 = 7; q2 >= 1; --q2) {
          if (bd[q2] < bd[q2 - 1]) {
            float tf = bd[q2]; bd[q2] = bd[q2 - 1]; bd[q2 - 1] = tf;
            int ti = bi[q2]; bi[q2] = bi[q2 - 1]; bi[q2 - 1] = ti;
          }
        }
      }
    }
    #pragma unroll
    for (int kk = 0; kk < 8; ++kk) nbr[((size_t)g * 1000 + n) * 8 + kk] = bi[kk];
  }
}

// ---------------- BatchNorm stats (deterministic two-stage) ----------------
__global__ __launch_bounds__(256) void bn_stat1(const float* __restrict__ hf, float* __restrict__ partial) {
  __shared__ float red[4][18];
  int row = blockIdx.x * 256 + threadIdx.x;
  float s[9], ss[9];
  #pragma unroll
  for (int f = 0; f < 9; ++f) {
    float v = hf[(size_t)row * 9 + f];
    s[f] = v;
    ss[f] = v * v;
  }
  for (int off = 32; off > 0; off >>= 1) {
    #pragma unroll
    for (int f = 0; f < 9; ++f) {
      s[f] += __shfl_down(s[f], off);
      ss[f] += __shfl_down(ss[f], off);
    }
  }
  int wid = threadIdx.x >> 6, lane = threadIdx.x & 63;
  if (lane == 0) {
    #pragma unroll
    for (int f = 0; f < 9; ++f) { red[wid][f] = s[f]; red[wid][9 + f] = ss[f]; }
  }
  __syncthreads();
  if (threadIdx.x < 18) {
    partial[(size_t)blockIdx.x * 18 + threadIdx.x] =
        red[0][threadIdx.x] + red[1][threadIdx.x] + red[2][threadIdx.x] + red[3][threadIdx.x];
  }
}

__global__ __launch_bounds__(256) void bn_stat2(const float* __restrict__ partial, float* __restrict__ stats) {
  __shared__ double sd[9][28], qd[9][28];
  int tid = threadIdx.x;
  if (tid < 252) {
    int f = tid % 9, gq = tid / 9;
    double s = 0.0, q = 0.0;
    for (int b = gq; b < 1000; b += 28) {
      s += (double)partial[b * 18 + f];
      q += (double)partial[b * 18 + 9 + f];
    }
    sd[f][gq] = s;
    qd[f][gq] = q;
  }
  __syncthreads();
  if (tid < 9) {
    double s = 0.0, q = 0.0;
    for (int g2 = 0; g2 < 28; ++g2) { s += sd[tid][g2]; q += qd[tid][g2]; }
    double mu = s / 256000.0;
    double var = q / 256000.0 - mu * mu;
    stats[tid] = (float)mu;
    stats[9 + tid] = (float)(1.0 / sqrt(var + 1e-5));
  }
}

// ---------------- Weight transpose: W[R][C] -> WT[C][R], one block per matrix ----------------
__global__ __launch_bounds__(256) void transpose_k(const float* __restrict__ src, float* __restrict__ dst,
                                                   int R, int C) {
  const float* s = src + (size_t)blockIdx.x * R * C;
  float* d = dst + (size_t)blockIdx.x * R * C;
  int n = R * C;
  for (int i = threadIdx.x; i < n; i += 256) {
    int rr = i / C, cc = i % C;
    d[cc * R + rr] = s[i];
  }
}

// ---------------- Embed: normalize + (9->80) ----------------
__global__ __launch_bounds__(320) void embed_kernel(const float* __restrict__ hf, const float* __restrict__ stats,
                                                    const float* __restrict__ gamma, const float* __restrict__ beta,
                                                    const float* __restrict__ We, const float* __restrict__ be,
                                                    float* __restrict__ h) {
  __shared__ __align__(16) float xs[40 * 9];
  size_t p0 = (size_t)blockIdx.x * 40;
  for (int i = threadIdx.x; i < 360; i += 320) {
    int f = i % 9;
    float x = hf[p0 * 9 + i];
    xs[i] = (x - stats[f]) * stats[9 + f] * gamma[f] + beta[f];
  }
  __syncthreads();
  int c = threadIdx.x % 80, pg = threadIdx.x / 80;
  float we[9];
  #pragma unroll
  for (int f = 0; f < 9; ++f) we[f] = We[f * 80 + c];
  float bias = be[c];
  for (int pp = 0; pp < 10; ++pp) {
    int p = pg * 10 + pp;
    float acc = 0.f;
    #pragma unroll
    for (int f = 0; f < 9; ++f) acc = fmaf(xs[p * 9 + f], we[f], acc);
    h[(p0 + p) * 80 + c] = acc + bias;
  }
}

// ---------------- K,V projection: transposed weights, float4 loads, all threads active ----------------
__global__ __launch_bounds__(320) void kv_kernel(const float* __restrict__ h, const float* __restrict__ WkT,
                                                 const float* __restrict__ WvT, float* __restrict__ kb,
                                                 float* __restrict__ vb) {
  __shared__ __align__(16) float hs[40 * 80];
  size_t p0 = (size_t)blockIdx.x * 40;
  {
    const float4* src = reinterpret_cast<const float4*>(h + p0 * 80);
    float4* dst = reinterpret_cast<float4*>(hs);
    for (int i = threadIdx.x; i < 800; i += 320) dst[i] = src[i];
  }
  __syncthreads();
  int tid = threadIdx.x;
  int c = tid % 80;    // this thread: k col c AND v col c
  int g = tid / 80;    // 4 rowgroups of 10 rows
  float acck[10] = {}, accv[10] = {};
  #pragma unroll
  for (int kc = 0; kc < 4; ++kc) {
    float wk[20], wv[20];
    const float4* wkp = reinterpret_cast<const float4*>(WkT + c * 80 + kc * 20);
    const float4* wvp = reinterpret_cast<const float4*>(WvT + c * 80 + kc * 20);
    #pragma unroll
    for (int q5 = 0; q5 < 5; ++q5) {
      float4 a = wkp[q5];
      wk[4 * q5 + 0] = a.x; wk[4 * q5 + 1] = a.y; wk[4 * q5 + 2] = a.z; wk[4 * q5 + 3] = a.w;
      float4 b = wvp[q5];
      wv[4 * q5 + 0] = b.x; wv[4 * q5 + 1] = b.y; wv[4 * q5 + 2] = b.z; wv[4 * q5 + 3] = b.w;
    }
    #pragma unroll
    for (int rr = 0; rr < 10; ++rr) {
      const float4* hp = reinterpret_cast<const float4*>(&hs[(g * 10 + rr) * 80 + kc * 20]);
      #pragma unroll
      for (int q5 = 0; q5 < 5; ++q5) {
        float4 hv = hp[q5];
        acck[rr] = fmaf(hv.x, wk[4 * q5 + 0], acck[rr]);
        acck[rr] = fmaf(hv.y, wk[4 * q5 + 1], acck[rr]);
        acck[rr] = fmaf(hv.z, wk[4 * q5 + 2], acck[rr]);
        acck[rr] = fmaf(hv.w, wk[4 * q5 + 3], acck[rr]);
        accv[rr] = fmaf(hv.x, wv[4 * q5 + 0], accv[rr]);
        accv[rr] = fmaf(hv.y, wv[4 * q5 + 1], accv[rr]);
        accv[rr] = fmaf(hv.z, wv[4 * q5 + 2], accv[rr]);
        accv[rr] = fmaf(hv.w, wv[4 * q5 + 3], accv[rr]);
      }
    }
  }
  #pragma unroll
  for (int rr = 0; rr < 10; ++rr) {
    int row = g * 10 + rr;
    kb[(p0 + row) * 80 + c] = acck[rr];
    vb[(p0 + row) * 80 + c] = accv[rr];
  }
}

// ---------------- Fused: q GEMM + attention + Wo (in-place) + FFN; qa/ts LDS-aliased ----------------
__global__ __launch_bounds__(320) void battn_kernel(const float* __restrict__ h, const float* __restrict__ kb,
                                                    const float* __restrict__ vb, const int* __restrict__ nbr,
                                                    const float* __restrict__ WqT, const float* __restrict__ WoT,
                                                    const float* __restrict__ bo, const float* __restrict__ W1T,
                                                    const float* __restrict__ b1, const float* __restrict__ W2T,
                                                    const float* __restrict__ b2, float* __restrict__ hout) {
  __shared__ __align__(16) float hs[40 * 84];    // h tile -> h+attn@Wo in place (stride 84)
  __shared__ __align__(16) float pool[40 * 164]; // qa (stride 84, first 3360 floats) then ts (stride 164)
  float* qa = pool;
  float* ts = pool;
  int b = blockIdx.x;
  int xcd = b & 7;
  int r = b >> 3;
  int graph = (xcd << 5) + (r / 25);
  int jb = r % 25;
  size_t gbase = (size_t)graph * 1000;
  size_t pbase = gbase + (size_t)jb * 40;
  int tid = threadIdx.x;
  // prefetch neighbor indices (depends only on tid) so attention's index-chase is hidden under q GEMM
  int pA = tid >> 3, hhA = tid & 7;
  int nb[8];
  #pragma unroll
  for (int kk = 0; kk < 8; ++kk) nb[kk] = nbr[(pbase + pA) * 8 + kk];
  // stage h tile into hs (stride 84)
  for (int i = tid; i < 800; i += 320) {
    int row = i / 20, kq = i % 20;
    float4 v = reinterpret_cast<const float4*>(h + (pbase + row) * 80)[kq];
    *reinterpret_cast<float4*>(&hs[row * 84 + kq * 4]) = v;
  }
  __syncthreads();
  // ---- q = h @ Wq : 40 colpairs x 8 rowgroups of 5 ----
  {
    int c2 = tid % 40, g = tid / 40;
    float acc0[5] = {}, acc1[5] = {};
    #pragma unroll
    for (int kc = 0; kc < 4; ++kc) {
      float w0[20], w1[20];
      const float4* wp0 = reinterpret_cast<const float4*>(WqT + c2 * 80 + kc * 20);
      const float4* wp1 = reinterpret_cast<const float4*>(WqT + (c2 + 40) * 80 + kc * 20);
      #pragma unroll
      for (int q5 = 0; q5 < 5; ++q5) {
        float4 a = wp0[q5];
        w0[4 * q5 + 0] = a.x; w0[4 * q5 + 1] = a.y; w0[4 * q5 + 2] = a.z; w0[4 * q5 + 3] = a.w;
        float4 bb2 = wp1[q5];
        w1[4 * q5 + 0] = bb2.x; w1[4 * q5 + 1] = bb2.y; w1[4 * q5 + 2] = bb2.z; w1[4 * q5 + 3] = bb2.w;
      }
      #pragma unroll
      for (int rr = 0; rr < 5; ++rr) {
        const float4* hp = reinterpret_cast<const float4*>(&hs[(g * 5 + rr) * 84 + kc * 20]);
        #pragma unroll
        for (int q5 = 0; q5 < 5; ++q5) {
          float4 hv = hp[q5];
          acc0[rr] = fmaf(hv.x, w0[4 * q5 + 0], acc0[rr]);
          acc0[rr] = fmaf(hv.y, w0[4 * q5 + 1], acc0[rr]);
          acc0[rr] = fmaf(hv.z, w0[4 * q5 + 2], acc0[rr]);
          acc0[rr] = fmaf(hv.w, w0[4 * q5 + 3], acc0[rr]);
          acc1[rr] = fmaf(hv.x, w1[4 * q5 + 0], acc1[rr]);
          acc1[rr] = fmaf(hv.y, w1[4 * q5 + 1], acc1[rr]);
          acc1[rr] = fmaf(hv.z, w1[4 * q5 + 2], acc1[rr]);
          acc1[rr] = fmaf(hv.w, w1[4 * q5 + 3], acc1[rr]);
        }
      }
    }
    #pragma unroll
    for (int rr = 0; rr < 5; ++rr) {
      int row = g * 5 + rr;
      qa[row * 84 + c2] = acc0[rr];
      qa[row * 84 + c2 + 40] = acc1[rr];
    }
  }
  __syncthreads();
  // ---- attention: thread = (point, head) ----
  {
    int p = pA, hh = hhA;
    float qv[10];
    #pragma unroll
    for (int d = 0; d < 10; ++d) qv[d] = qa[p * 84 + hh * 10 + d];
    float sv[8];
    float denom = 0.f;
    #pragma unroll
    for (int kk = 0; kk < 8; ++kk) {
      const float2* kr = reinterpret_cast<const float2*>(kb + (gbase + nb[kk]) * 80 + hh * 10);
      float acc = 0.f;
      #pragma unroll
      for (int d2 = 0; d2 < 5; ++d2) {
        float2 kv2 = kr[d2];
        acc = fmaf(qv[2 * d2], kv2.x, acc);
        acc = fmaf(qv[2 * d2 + 1], kv2.y, acc);
      }
      float s = acc * 0.31622776601683794f;
      s = fminf(fmaxf(s, -5.f), 5.f);
      s = expf(s);
      sv[kk] = s;
      denom += s;
    }
    float wV[10] = {0, 0, 0, 0, 0, 0, 0, 0, 0, 0};
    #pragma unroll
    for (int kk = 0; kk < 8; ++kk) {
      const float2* vr = reinterpret_cast<const float2*>(vb + (gbase + nb[kk]) * 80 + hh * 10);
      #pragma unroll
      for (int d2 = 0; d2 < 5; ++d2) {
        float2 vv = vr[d2];
        wV[2 * d2] = fmaf(sv[kk], vv.x, wV[2 * d2]);
        wV[2 * d2 + 1] = fmaf(sv[kk], vv.y, wV[2 * d2 + 1]);
      }
    }
    float dn = denom + 1e-6f;
    #pragma unroll
    for (int d = 0; d < 10; ++d) qa[p * 84 + hh * 10 + d] = wV[d] / dn;
  }
  __syncthreads();
  // ---- hs += attn @ Wo + bo (in place) ----
  {
    int c2 = tid % 40, g = tid / 40;
    float acc0[5] = {}, acc1[5] = {};
    #pragma unroll
    for (int kc = 0; kc < 4; ++kc) {
      float w0[20], w1[20];
      const float4* wp0 = reinterpret_cast<const float4*>(WoT + c2 * 80 + kc * 20);
      const float4* wp1 = reinterpret_cast<const float4*>(WoT + (c2 + 40) * 80 + kc * 20);
      #pragma unroll
      for (int q5 = 0; q5 < 5; ++q5) {
        float4 a = wp0[q5];
        w0[4 * q5 + 0] = a.x; w0[4 * q5 + 1] = a.y; w0[4 * q5 + 2] = a.z; w0[4 * q5 + 3] = a.w;
        float4 bb2 = wp1[q5];
        w1[4 * q5 + 0] = bb2.x; w1[4 * q5 + 1] = bb2.y; w1[4 * q5 + 2] = bb2.z; w1[4 * q5 + 3] = bb2.w;
      }
      #pragma unroll
      for (int rr = 0; rr < 5; ++rr) {
        const float4* hp = reinterpret_cast<const float4*>(&qa[(g * 5 + rr) * 84 + kc * 20]);
        #pragma unroll
        for (int q5 = 0; q5 < 5; ++q5) {
          float4 hv = hp[q5];
          acc0[rr] = fmaf(hv.x, w0[4 * q5 + 0], acc0[rr]);
          acc0[rr] = fmaf(hv.y, w0[4 * q5 + 1], acc0[rr]);
          acc0[rr] = fmaf(hv.z, w0[4 * q5 + 2], acc0[rr]);
          acc0[rr] = fmaf(hv.w, w0[4 * q5 + 3], acc0[rr]);
          acc1[rr] = fmaf(hv.x, w1[4 * q5 + 0], acc1[rr]);
          acc1[rr] = fmaf(hv.y, w1[4 * q5 + 1], acc1[rr]);
          acc1[rr] = fmaf(hv.z, w1[4 * q5 + 2], acc1[rr]);
          acc1[rr] = fmaf(hv.w, w1[4 * q5 + 3], acc1[rr]);
        }
      }
    }
    float bias0 = bo[c2], bias1 = bo[c2 + 40];
    #pragma unroll
    for (int rr = 0; rr < 5; ++rr) {
      int row = g * 5 + rr;
      hs[row * 84 + c2] += acc0[rr] + bias0;
      hs[row * 84 + c2 + 40] += acc1[rr] + bias1;
    }
  }
  __syncthreads();
  // ---- ts = relu(h2 @ W1 + b1): overwrites qa region (dead) ----
  {
    int c2 = tid % 80, g = tid / 80;
    float acc0[10] = {}, acc1[10] = {};
    #pragma unroll
    for (int kc = 0; kc < 4; ++kc) {
      float w0[20], w1[20];
      const float4* wp0 = reinterpret_cast<const float4*>(W1T + c2 * 80 + kc * 20);
      const float4* wp1 = reinterpret_cast<const float4*>(W1T + (c2 + 80) * 80 + kc * 20);
      #pragma unroll
      for (int q5 = 0; q5 < 5; ++q5) {
        float4 a = wp0[q5];
        w0[4 * q5 + 0] = a.x; w0[4 * q5 + 1] = a.y; w0[4 * q5 + 2] = a.z; w0[4 * q5 + 3] = a.w;
        float4 bb2 = wp1[q5];
        w1[4 * q5 + 0] = bb2.x; w1[4 * q5 + 1] = bb2.y; w1[4 * q5 + 2] = bb2.z; w1[4 * q5 + 3] = bb2.w;
      }
      #pragma unroll
      for (int rr = 0; rr < 10; ++rr) {
        const float4* hp = reinterpret_cast<const float4*>(&hs[(g * 10 + rr) * 84 + kc * 20]);
        #pragma unroll
        for (int q5 = 0; q5 < 5; ++q5) {
          float4 hv = hp[q5];
          acc0[rr] = fmaf(hv.x, w0[4 * q5 + 0], acc0[rr]);
          acc0[rr] = fmaf(hv.y, w0[4 * q5 + 1], acc0[rr]);
          acc0[rr] = fmaf(hv.z, w0[4 * q5 + 2], acc0[rr]);
          acc0[rr] = fmaf(hv.w, w0[4 * q5 + 3], acc0[rr]);
          acc1[rr] = fmaf(hv.x, w1[4 * q5 + 0], acc1[rr]);
          acc1[rr] = fmaf(hv.y, w1[4 * q5 + 1], acc1[rr]);
          acc1[rr] = fmaf(hv.z, w1[4 * q5 + 2], acc1[rr]);
          acc1[rr] = fmaf(hv.w, w1[4 * q5 + 3], acc1[rr]);
        }
      }
    }
    float bias0 = b1[c2], bias1 = b1[c2 + 80];
    #pragma unroll
    for (int rr = 0; rr < 10; ++rr) {
      int row = g * 10 + rr;
      ts[row * 164 + c2] = fmaxf(acc0[rr] + bias0, 0.f);
      ts[row * 164 + c2 + 80] = fmaxf(acc1[rr] + bias1, 0.f);
    }
  }
  __syncthreads();
  // ---- hout = h2 + ts @ W2 + b2: 40 colpairs x 8 rowgroups of 5, K=160 ----
  {
    int c2 = tid % 40, g = tid / 40;
    float acc0[5] = {}, acc1[5] = {};
    #pragma unroll
    for (int kc = 0; kc < 8; ++kc) {
      float w0[20], w1[20];
      const float4* wp0 = reinterpret_cast<const float4*>(W2T + c2 * 160 + kc * 20);
      const float4* wp1 = reinterpret_cast<const float4*>(W2T + (c2 + 40) * 160 + kc * 20);
      #pragma unroll
      for (int q5 = 0; q5 < 5; ++q5) {
        float4 a = wp0[q5];
        w0[4 * q5 + 0] = a.x; w0[4 * q5 + 1] = a.y; w0[4 * q5 + 2] = a.z; w0[4 * q5 + 3] = a.w;
        float4 bb2 = wp1[q5];
        w1[4 * q5 + 0] = bb2.x; w1[4 * q5 + 1] = bb2.y; w1[4 * q5 + 2] = bb2.z; w1[4 * q5 + 3] = bb2.w;
      }
      #pragma unroll
      for (int rr = 0; rr < 5; ++rr) {
        const float4* hp = reinterpret_cast<const float4*>(&ts[(g * 5 + rr) * 164 + kc * 20]);
        #pragma unroll
        for (int q5 = 0; q5 < 5; ++q5) {
          float4 hv = hp[q5];
          acc0[rr] = fmaf(hv.x, w0[4 * q5 + 0], acc0[rr]);
          acc0[rr] = fmaf(hv.y, w0[4 * q5 + 1], acc0[rr]);
          acc0[rr] = fmaf(hv.z, w0[4 * q5 + 2], acc0[rr]);
          acc0[rr] = fmaf(hv.w, w0[4 * q5 + 3], acc0[rr]);
          acc1[rr] = fmaf(hv.x, w1[4 * q5 + 0], acc1[rr]);
          acc1[rr] = fmaf(hv.y, w1[4 * q5 + 1], acc1[rr]);
          acc1[rr] = fmaf(hv.z, w1[4 * q5 + 2], acc1[rr]);
          acc1[rr] = fmaf(hv.w, w1[4 * q5 + 3], acc1[rr]);
        }
      }
    }
    float bias0 = b2[c2], bias1 = b2[c2 + 40];
    #pragma unroll
    for (int rr = 0; rr < 5; ++rr) {
      int row = g * 5 + rr;
      hout[(pbase + row) * 80 + c2] = hs[row * 84 + c2] + acc0[rr] + bias0;
      hout[(pbase + row) * 80 + c2 + 40] = hs[row * 84 + c2 + 40] + acc1[rr] + bias1;
    }
  }
}

// ---------------- Readout MLP 80->40->20->64->{3,1} ----------------
__global__ __launch_bounds__(320) void readout_kernel(const float* __restrict__ h, const float* __restrict__ Wr0,
                                                      const float* __restrict__ br0, const float* __restrict__ Wr1,
                                                      const float* __restrict__ br1, const float* __restrict__ Wr2,
                                                      const float* __restrict__ br2, const float* __restrict__ Wc,
                                                      const float* __restrict__ Wb, const float* __restrict__ bb,
                                                      float* __restrict__ out) {
  __shared__ __align__(16) float hs[3200];
  __shared__ __align__(16) float y0s[40 * 40];
  __shared__ __align__(16) float y1s[40 * 20];
  __shared__ __align__(16) float y2s[40 * 64];
  size_t p0 = (size_t)blockIdx.x * 40;
  int tid = threadIdx.x;
  {
    const float4* src = reinterpret_cast<const float4*>(h + p0 * 80);
    float4* dst = reinterpret_cast<float4*>(hs);
    for (int i = tid; i < 800; i += 320) dst[i] = src[i];
  }
  __syncthreads();
  {  // y0 = relu(h@Wr0 + br0)
    int c = tid % 40, grp = tid / 40;  // 0..7
    if (grp < 5) {
      float wcol[80];
      #pragma unroll
      for (int kk = 0; kk < 80; ++kk) wcol[kk] = Wr0[kk * 40 + c];
      float bias = br0[c];
      float acc[8] = {};
      #pragma unroll
      for (int j = 0; j < 8; ++j) {
        const float4* r4 = reinterpret_cast<const float4*>(hs + (grp * 8 + j) * 80);
        #pragma unroll
        for (int kq = 0; kq < 20; ++kq) {
          float4 hv = r4[kq];
          acc[j] = fmaf(hv.x, wcol[4 * kq + 0], acc[j]);
          acc[j] = fmaf(hv.y, wcol[4 * kq + 1], acc[j]);
          acc[j] = fmaf(hv.z, wcol[4 * kq + 2], acc[j]);
          acc[j] = fmaf(hv.w, wcol[4 * kq + 3], acc[j]);
        }
      }
      #pragma unroll
      for (int j = 0; j < 8; ++j) y0s[(grp * 8 + j) * 40 + c] = fmaxf(acc[j] + bias, 0.f);
    }
  }
  __syncthreads();
  {  // y1 = relu(y0@Wr1 + br1)
    int c = tid % 20, grp = tid / 20;  // 0..15
    if (grp < 5) {
      float wcol[40];
      #pragma unroll
      for (int kk = 0; kk < 40; ++kk) wcol[kk] = Wr1[kk * 20 + c];
      float bias = br1[c];
      float acc[8] = {};
      #pragma unroll
      for (int j = 0; j < 8; ++j) {
        const float4* r4 = reinterpret_cast<const float4*>(y0s + (grp * 8 + j) * 40);
        #pragma unroll
        for (int kq = 0; kq < 10; ++kq) {
          float4 hv = r4[kq];
          acc[j] = fmaf(hv.x, wcol[4 * kq + 0], acc[j]);
          acc[j] = fmaf(hv.y, wcol[4 * kq + 1], acc[j]);
          acc[j] = fmaf(hv.z, wcol[4 * kq + 2], acc[j]);
          acc[j] = fmaf(hv.w, wcol[4 * kq + 3], acc[j]);
        }
      }
      #pragma unroll
      for (int j = 0; j < 8; ++j) y1s[(grp * 8 + j) * 20 + c] = fmaxf(acc[j] + bias, 0.f);
    }
  }
  __syncthreads();
  {  // y2 = y1@Wr2 + br2
    int c = tid % 64, grp = tid / 64;  // 0..4
    float wcol[20];
    #pragma unroll
    for (int kk = 0; kk < 20; ++kk) wcol[kk] = Wr2[kk * 64 + c];
    float bias = br2[c];
    float acc[8] = {};
    #pragma unroll
    for (int j = 0; j < 8; ++j) {
      const float4* r4 = reinterpret_cast<const float4*>(y1s + (grp * 8 + j) * 20);
      #pragma unroll
      for (int kq = 0; kq < 5; ++kq) {
        float4 hv = r4[kq];
        acc[j] = fmaf(hv.x, wcol[4 * kq + 0], acc[j]);
        acc[j] = fmaf(hv.y, wcol[4 * kq + 1], acc[j]);
        acc[j] = fmaf(hv.z, wcol[4 * kq + 2], acc[j]);
        acc[j] = fmaf(hv.w, wcol[4 * kq + 3], acc[j]);
      }
    }
    #pragma unroll
    for (int j = 0; j < 8; ++j) y2s[(grp * 8 + j) * 64 + c] = acc[j] + bias;
  }
  __syncthreads();
  {  // out: cc = y2@Wc, beta = y2@Wb + bb
    int c = tid % 4, p = tid / 4;
    if (p < 40) {
      float wcol[64];
      if (c < 3) {
        #pragma unroll
        for (int kk = 0; kk < 64; ++kk) wcol[kk] = Wc[kk * 3 + c];
      } else {
        #pragma unroll
        for (int kk = 0; kk < 64; ++kk) wcol[kk] = Wb[kk];
      }
      float acc = 0.f;
      #pragma unroll
      for (int kk = 0; kk < 64; ++kk) acc = fmaf(y2s[p * 64 + kk], wcol[kk], acc);
      if (c == 3) acc += bb[0];
      out[(p0 + p) * 4 + c] = acc;
    }
  }
}

extern "C" void kernel_launch(void* const* d_in, const int* in_sizes, int n_in,
                              void* d_out, int out_size, void* d_ws, size_t ws_size,
                              hipStream_t stream) {
  const float* hf = (const float*)d_in[0];
  const float* gamma = (const float*)d_in[1];
  const float* beta = (const float*)d_in[2];
  const float* We = (const float*)d_in[3];
  const float* be = (const float*)d_in[4];
  const float* Wq = (const float*)d_in[5];
  const float* Wk = (const float*)d_in[6];
  const float* Wv = (const float*)d_in[7];
  const float* Wo = (const float*)d_in[8];
  const float* bo = (const float*)d_in[9];
  const float* W1 = (const float*)d_in[10];
  const float* b1 = (const float*)d_in[11];
  const float* W2 = (const float*)d_in[12];
  const float* b2 = (const float*)d_in[13];
  const float* Wr0 = (const float*)d_in[14];
  const float* br0 = (const float*)d_in[15];
  const float* Wr1 = (const float*)d_in[16];
  const float* br1 = (const float*)d_in[17];
  const float* Wr2 = (const float*)d_in[18];
  const float* br2 = (const float*)d_in[19];
  const float* Wc = (const float*)d_in[20];
  const float* Wb = (const float*)d_in[21];
  const float* bb = (const float*)d_in[22];
  float* out = (float*)d_out;

  char* wsp = (char*)d_ws;
  int* nbr = (int*)wsp;            wsp += (size_t)256000 * 8 * 4;
  float* hA = (float*)wsp;         wsp += (size_t)256000 * 80 * 4;
  float* kbuf = (float*)wsp;       wsp += (size_t)256000 * 80 * 4;
  float* vbuf = (float*)wsp;       wsp += (size_t)256000 * 80 * 4;
  float* partial = (float*)wsp;    wsp += (size_t)1000 * 18 * 4;
  float* stats = (float*)wsp;      wsp += 128;  // 18 floats = 72 B (r3 bug: 64 B overlapped WqT)
  float* WqT = (float*)wsp;        wsp += (size_t)10 * 6400 * 4;
  float* WoT = (float*)wsp;        wsp += (size_t)10 * 6400 * 4;
  float* WkT = (float*)wsp;        wsp += (size_t)10 * 6400 * 4;
  float* WvT = (float*)wsp;        wsp += (size_t)10 * 6400 * 4;
  float* W1T = (float*)wsp;        wsp += (size_t)10 * 12800 * 4;
  float* W2T = (float*)wsp;        wsp += (size_t)10 * 12800 * 4;

  knn_kernel<<<1024, 256, 0, stream>>>(hf, nbr);
  bn_stat1<<<1000, 256, 0, stream>>>(hf, partial);
  bn_stat2<<<1, 256, 0, stream>>>(partial, stats);
  transpose_k<<<10, 256, 0, stream>>>(Wq, WqT, 80, 80);
  transpose_k<<<10, 256, 0, stream>>>(Wo, WoT, 80, 80);
  transpose_k<<<10, 256, 0, stream>>>(Wk, WkT, 80, 80);
  transpose_k<<<10, 256, 0, stream>>>(Wv, WvT, 80, 80);
  transpose_k<<<10, 256, 0, stream>>>(W1, W1T, 80, 160);
  transpose_k<<<10, 256, 0, stream>>>(W2, W2T, 160, 80);
  embed_kernel<<<6400, 320, 0, stream>>>(hf, stats, gamma, beta, We, be, hA);
  for (int l = 0; l < 10; ++l) {
    kv_kernel<<<6400, 320, 0, stream>>>(hA, WkT + (size_t)l * 6400, WvT + (size_t)l * 6400, kbuf, vbuf);
    battn_kernel<<<6400, 320, 0, stream>>>(hA, kbuf, vbuf, nbr,
                                           WqT + (size_t)l * 6400, WoT + (size_t)l * 6400, bo + (size_t)l * 80,
                                           W1T + (size_t)l * 12800, b1 + (size_t)l * 160,
                                           W2T + (size_t)l * 12800, b2 + (size_t)l * 80, hA);
  }
  readout_kernel<<<6400, 320, 0, stream>>>(hA, Wr0, br0, Wr1, br1, Wr2, br2, Wc, Wb, bb, out);
}

// Round 6
// 3553.609 us; speedup vs baseline: 14.6346x; 2.5063x over previous
//
#include <hip/hip_runtime.h>
#include <cstdint>
#include <cstddef>

// G=256 graphs, NP=1000 points, K=8 neighbors, H=8 heads, DH=10, D=80, NL=10 layers
// GEMMs via split-bf16 MFMA: x = hi + lo (bf16 each); C = Ahi*Bhi + Ahi*Blo + Alo*Bhi (~f32 accuracy).

typedef __attribute__((ext_vector_type(8))) short short8v;
typedef __attribute__((ext_vector_type(4))) float f32x4;

#define MFMA16(ACC, A, B) ACC = __builtin_amdgcn_mfma_f32_16x16x32_bf16(A, B, ACC, 0, 0, 0)
#define MF3(ACC, AH, AL, BH, BL) { MFMA16(ACC, AH, BH); MFMA16(ACC, AH, BL); MFMA16(ACC, AL, BH); }

__device__ __forceinline__ void splitbf(float x, unsigned short& hi, unsigned short& lo) {
  unsigned u = __float_as_uint(x);
  unsigned r = u + 0x7FFFu + ((u >> 16) & 1u);
  hi = (unsigned short)(r >> 16);
  float hf = __uint_as_float(((unsigned)hi) << 16);
  float lf = x - hf;
  unsigned u2 = __float_as_uint(lf);
  unsigned r2 = u2 + 0x7FFFu + ((u2 >> 16) & 1u);
  lo = (unsigned short)(r2 >> 16);
}

// ---------------- KNN: exact reference-order arithmetic, stable tie-break ----------------
__global__ __launch_bounds__(256) void knn_kernel(const float* __restrict__ hf, int* __restrict__ nbr) {
  __shared__ float cs[3000];
  int b = blockIdx.x;
  int g = b >> 2;
  int q = b & 3;
  for (int i = threadIdx.x; i < 3000; i += 256) {
    cs[i] = hf[((size_t)g * 1000 + (i / 3)) * 9 + (i % 3)];
  }
  __syncthreads();
  int tid = threadIdx.x;
  if (tid < 250) {
    int n = q * 250 + tid;
    float cx = cs[n * 3 + 0], cy = cs[n * 3 + 1], cz = cs[n * 3 + 2];
    float bd[8];
    int bi[8];
    #pragma unroll
    for (int q2 = 0; q2 < 8; ++q2) { bd[q2] = 3.402823466e38f; bi[q2] = 0; }
    for (int j = 0; j < 1000; ++j) {
      float dx = __fsub_rn(cx, cs[j * 3 + 0]);
      float dy = __fsub_rn(cy, cs[j * 3 + 1]);
      float dz = __fsub_rn(cz, cs[j * 3 + 2]);
      float d2 = __fadd_rn(__fadd_rn(__fmul_rn(dx, dx), __fmul_rn(dy, dy)), __fmul_rn(dz, dz));
      if (d2 < bd[7]) {
        bd[7] = d2; bi[7] = j;
        #pragma unroll
        for (int q2 = 7; q2 >= 1; --q2) {
          if (bd[q2] < bd[q2 - 1]) {
            float tf = bd[q2]; bd[q2] = bd[q2 - 1]; bd[q2 - 1] = tf;
            int ti = bi[q2]; bi[q2] = bi[q2 - 1]; bi[q2 - 1] = ti;
          }
        }
      }
    }
    #pragma unroll
    for (int kk = 0; kk < 8; ++kk) nbr[((size_t)g * 1000 + n) * 8 + kk] = bi[kk];
  }
}

// ---------------- BatchNorm stats (deterministic two-stage) ----------------
__global__ __launch_bounds__(256) void bn_stat1(const float* __restrict__ hf, float* __restrict__ partial) {
  __shared__ float red[4][18];
  int row = blockIdx.x * 256 + threadIdx.x;
  float s[9], ss[9];
  #pragma unroll
  for (int f = 0; f < 9; ++f) {
    float v = hf[(size_t)row * 9 + f];
    s[f] = v;
    ss[f] = v * v;
  }
  for (int off = 32; off > 0; off >>= 1) {
    #pragma unroll
    for (int f = 0; f < 9; ++f) {
      s[f] += __shfl_down(s[f], off);
      ss[f] += __shfl_down(ss[f], off);
    }
  }
  int wid = threadIdx.x >> 6, lane = threadIdx.x & 63;
  if (lane == 0) {
    #pragma unroll
    for (int f = 0; f < 9; ++f) { red[wid][f] = s[f]; red[wid][9 + f] = ss[f]; }
  }
  __syncthreads();
  if (threadIdx.x < 18) {
    partial[(size_t)blockIdx.x * 18 + threadIdx.x] =
        red[0][threadIdx.x] + red[1][threadIdx.x] + red[2][threadIdx.x] + red[3][threadIdx.x];
  }
}

__global__ __launch_bounds__(256) void bn_stat2(const float* __restrict__ partial, float* __restrict__ stats) {
  __shared__ double sd[9][28], qd[9][28];
  int tid = threadIdx.x;
  if (tid < 252) {
    int f = tid % 9, gq = tid / 9;
    double s = 0.0, q = 0.0;
    for (int b = gq; b < 1000; b += 28) {
      s += (double)partial[b * 18 + f];
      q += (double)partial[b * 18 + 9 + f];
    }
    sd[f][gq] = s;
    qd[f][gq] = q;
  }
  __syncthreads();
  if (tid < 9) {
    double s = 0.0, q = 0.0;
    for (int g2 = 0; g2 < 28; ++g2) { s += sd[tid][g2]; q += qd[tid][g2]; }
    double mu = s / 256000.0;
    double var = q / 256000.0 - mu * mu;
    stats[tid] = (float)mu;
    stats[9 + tid] = (float)(1.0 / sqrt(var + 1e-5));
  }
}

// ---------------- Weight split-transpose: W[R][C] -> BT_hi/lo[C][KS] bf16, k-pad zeroed ----------------
__global__ __launch_bounds__(256) void split_tr(const float* __restrict__ src, unsigned short* __restrict__ dhi,
                                                unsigned short* __restrict__ dlo, int R, int C, int KS) {
  const float* s = src + (size_t)blockIdx.x * R * C;
  unsigned short* dh = dhi + (size_t)blockIdx.x * C * KS;
  unsigned short* dl = dlo + (size_t)blockIdx.x * C * KS;
  int n = C * KS;
  for (int i = threadIdx.x; i < n; i += 256) {
    int c = i / KS, kk = i % KS;
    float v = (kk < R) ? s[kk * C + c] : 0.f;
    unsigned short h, l;
    splitbf(v, h, l);
    dh[i] = h;
    dl[i] = l;
  }
}

// ---------------- Embed: normalize + (9->80) ----------------
__global__ __launch_bounds__(320) void embed_kernel(const float* __restrict__ hf, const float* __restrict__ stats,
                                                    const float* __restrict__ gamma, const float* __restrict__ beta,
                                                    const float* __restrict__ We, const float* __restrict__ be,
                                                    float* __restrict__ h) {
  __shared__ __align__(16) float xs[40 * 9];
  size_t p0 = (size_t)blockIdx.x * 40;
  for (int i = threadIdx.x; i < 360; i += 320) {
    int f = i % 9;
    float x = hf[p0 * 9 + i];
    xs[i] = (x - stats[f]) * stats[9 + f] * gamma[f] + beta[f];
  }
  __syncthreads();
  int c = threadIdx.x % 80, pg = threadIdx.x / 80;
  float we[9];
  #pragma unroll
  for (int f = 0; f < 9; ++f) we[f] = We[f * 80 + c];
  float bias = be[c];
  for (int pp = 0; pp < 10; ++pp) {
    int p = pg * 10 + pp;
    float acc = 0.f;
    #pragma unroll
    for (int f = 0; f < 9; ++f) acc = fmaf(xs[p * 9 + f], we[f], acc);
    h[(p0 + p) * 80 + c] = acc + bias;
  }
}

// ---------------- K,V projection via split-bf16 MFMA ----------------
__global__ __launch_bounds__(320) void kv_kernel(const float* __restrict__ h,
                                                 const unsigned short* __restrict__ WkH, const unsigned short* __restrict__ WkL,
                                                 const unsigned short* __restrict__ WvH, const unsigned short* __restrict__ WvL,
                                                 float* __restrict__ kb, float* __restrict__ vb) {
  __shared__ __align__(16) unsigned short ahi[48 * 104];
  __shared__ __align__(16) unsigned short alo[48 * 104];
  size_t p0 = (size_t)blockIdx.x * 40;
  int tid = threadIdx.x;
  int lane = tid & 63, wv = tid >> 6;
  int fr = lane & 15, fq = lane >> 4;
  // stage + split h (40x80, stride 104)
  for (int i = tid; i < 800; i += 320) {
    int row = i / 20, kq = i % 20;
    float4 v = reinterpret_cast<const float4*>(h + (p0 + row) * 80)[kq];
    unsigned short h0, l0, h1, l1, h2, l2, h3, l3;
    splitbf(v.x, h0, l0); splitbf(v.y, h1, l1); splitbf(v.z, h2, l2); splitbf(v.w, h3, l3);
    int off = row * 104 + kq * 4;
    *reinterpret_cast<unsigned*>(&ahi[off]) = (unsigned)h0 | ((unsigned)h1 << 16);
    *reinterpret_cast<unsigned*>(&ahi[off + 2]) = (unsigned)h2 | ((unsigned)h3 << 16);
    *reinterpret_cast<unsigned*>(&alo[off]) = (unsigned)l0 | ((unsigned)l1 << 16);
    *reinterpret_cast<unsigned*>(&alo[off + 2]) = (unsigned)l2 | ((unsigned)l3 << 16);
  }
  // zero k-pad cols 80..95 for all 48 rows
  for (int i = tid; i < 384; i += 320) {
    int row = i >> 3, kk = 80 + ((i & 7) << 1);
    int off = row * 104 + kk;
    *reinterpret_cast<unsigned*>(&ahi[off]) = 0u;
    *reinterpret_cast<unsigned*>(&alo[off]) = 0u;
  }
  __syncthreads();
  int bcol = wv * 16 + fr;
  f32x4 ck0 = {0.f, 0.f, 0.f, 0.f}, ck1 = ck0, ck2 = ck0;
  f32x4 cv0 = ck0, cv1 = ck0, cv2 = ck0;
  #pragma unroll
  for (int ks = 0; ks < 3; ++ks) {
    int boff = bcol * 96 + ks * 32 + fq * 8;
    short8v bkh = *reinterpret_cast<const short8v*>(WkH + boff);
    short8v bkl = *reinterpret_cast<const short8v*>(WkL + boff);
    short8v bvh = *reinterpret_cast<const short8v*>(WvH + boff);
    short8v bvl = *reinterpret_cast<const short8v*>(WvL + boff);
    int a0 = (0 * 16 + fr) * 104 + ks * 32 + fq * 8;
    int a1 = (1 * 16 + fr) * 104 + ks * 32 + fq * 8;
    int a2 = (2 * 16 + fr) * 104 + ks * 32 + fq * 8;
    short8v ah0 = *reinterpret_cast<const short8v*>(ahi + a0);
    short8v al0 = *reinterpret_cast<const short8v*>(alo + a0);
    MF3(ck0, ah0, al0, bkh, bkl); MF3(cv0, ah0, al0, bvh, bvl);
    short8v ah1 = *reinterpret_cast<const short8v*>(ahi + a1);
    short8v al1 = *reinterpret_cast<const short8v*>(alo + a1);
    MF3(ck1, ah1, al1, bkh, bkl); MF3(cv1, ah1, al1, bvh, bvl);
    short8v ah2 = *reinterpret_cast<const short8v*>(ahi + a2);
    short8v al2 = *reinterpret_cast<const short8v*>(alo + a2);
    MF3(ck2, ah2, al2, bkh, bkl); MF3(cv2, ah2, al2, bvh, bvl);
  }
  #pragma unroll
  for (int j = 0; j < 4; ++j) {
    int r0 = fq * 4 + j;
    kb[(p0 + r0) * 80 + bcol] = ck0[j];
    vb[(p0 + r0) * 80 + bcol] = cv0[j];
    int r1 = 16 + r0;
    kb[(p0 + r1) * 80 + bcol] = ck1[j];
    vb[(p0 + r1) * 80 + bcol] = cv1[j];
    int r2 = 32 + r0;
    if (r2 < 40) {
      kb[(p0 + r2) * 80 + bcol] = ck2[j];
      vb[(p0 + r2) * 80 + bcol] = cv2[j];
    }
  }
}

// ---------------- Fused layer: q MFMA + attention(f32) + Wo MFMA + FFN MFMA ----------------
__global__ __launch_bounds__(320) void battn_kernel(const float* __restrict__ h, const float* __restrict__ kb,
                                                    const float* __restrict__ vb, const int* __restrict__ nbr,
                                                    const unsigned short* __restrict__ WqH, const unsigned short* __restrict__ WqL,
                                                    const unsigned short* __restrict__ WoH, const unsigned short* __restrict__ WoL,
                                                    const float* __restrict__ bo,
                                                    const unsigned short* __restrict__ W1H, const unsigned short* __restrict__ W1L,
                                                    const float* __restrict__ b1,
                                                    const unsigned short* __restrict__ W2H, const unsigned short* __restrict__ W2L,
                                                    const float* __restrict__ b2, float* __restrict__ hout) {
  __shared__ __align__(16) unsigned short ahi[48 * 168];  // activation hi-split (K up to 160, stride 168)
  __shared__ __align__(16) unsigned short alo[48 * 168];  // activation lo-split
  __shared__ __align__(16) float qa[40 * 84];             // q f32, then h2 f32 (stride 84)
  int b = blockIdx.x;
  int xcd = b & 7;
  int r = b >> 3;
  int graph = (xcd << 5) + (r / 25);
  int jb = r % 25;
  size_t gbase = (size_t)graph * 1000;
  size_t pbase = gbase + (size_t)jb * 40;
  int tid = threadIdx.x;
  int lane = tid & 63, wv = tid >> 6;
  int fr = lane & 15, fq = lane >> 4;
  // prefetch neighbor indices for attention
  int pA = tid >> 3, hhA = tid & 7;
  int nb[8];
  #pragma unroll
  for (int kk = 0; kk < 8; ++kk) nb[kk] = nbr[(pbase + pA) * 8 + kk];
  // stage + split h (40x80 -> stride 168)
  for (int i = tid; i < 800; i += 320) {
    int row = i / 20, kq = i % 20;
    float4 v = reinterpret_cast<const float4*>(h + (pbase + row) * 80)[kq];
    unsigned short h0, l0, h1, l1, h2_, l2, h3, l3;
    splitbf(v.x, h0, l0); splitbf(v.y, h1, l1); splitbf(v.z, h2_, l2); splitbf(v.w, h3, l3);
    int off = row * 168 + kq * 4;
    *reinterpret_cast<unsigned*>(&ahi[off]) = (unsigned)h0 | ((unsigned)h1 << 16);
    *reinterpret_cast<unsigned*>(&ahi[off + 2]) = (unsigned)h2_ | ((unsigned)h3 << 16);
    *reinterpret_cast<unsigned*>(&alo[off]) = (unsigned)l0 | ((unsigned)l1 << 16);
    *reinterpret_cast<unsigned*>(&alo[off + 2]) = (unsigned)l2 | ((unsigned)l3 << 16);
  }
  // zero k-pad cols 80..95 (stays valid for q, Wo, W1 inputs; ts overwrites with real data for W2)
  for (int i = tid; i < 384; i += 320) {
    int row = i >> 3, kk = 80 + ((i & 7) << 1);
    int off = row * 168 + kk;
    *reinterpret_cast<unsigned*>(&ahi[off]) = 0u;
    *reinterpret_cast<unsigned*>(&alo[off]) = 0u;
  }
  __syncthreads();
  int bcol = wv * 16 + fr;  // this wave's output column (for N=80 GEMMs)
  // ---- q = h @ Wq (MFMA) -> qa f32 ----
  {
    f32x4 c0 = {0.f, 0.f, 0.f, 0.f}, c1 = c0, c2 = c0;
    #pragma unroll
    for (int ks = 0; ks < 3; ++ks) {
      int boff = bcol * 96 + ks * 32 + fq * 8;
      short8v bh = *reinterpret_cast<const short8v*>(WqH + boff);
      short8v bl = *reinterpret_cast<const short8v*>(WqL + boff);
      int a0 = (0 * 16 + fr) * 168 + ks * 32 + fq * 8;
      int a1 = (1 * 16 + fr) * 168 + ks * 32 + fq * 8;
      int a2 = (2 * 16 + fr) * 168 + ks * 32 + fq * 8;
      short8v ah0 = *reinterpret_cast<const short8v*>(ahi + a0);
      short8v al0 = *reinterpret_cast<const short8v*>(alo + a0);
      MF3(c0, ah0, al0, bh, bl);
      short8v ah1 = *reinterpret_cast<const short8v*>(ahi + a1);
      short8v al1 = *reinterpret_cast<const short8v*>(alo + a1);
      MF3(c1, ah1, al1, bh, bl);
      short8v ah2 = *reinterpret_cast<const short8v*>(ahi + a2);
      short8v al2 = *reinterpret_cast<const short8v*>(alo + a2);
      MF3(c2, ah2, al2, bh, bl);
    }
    #pragma unroll
    for (int j = 0; j < 4; ++j) {
      int r0 = fq * 4 + j;
      qa[r0 * 84 + bcol] = c0[j];
      qa[(16 + r0) * 84 + bcol] = c1[j];
      int r2 = 32 + r0;
      if (r2 < 40) qa[r2 * 84 + bcol] = c2[j];
    }
  }
  __syncthreads();
  // ---- attention (f32 exact) ; writes attn split into ahi/alo ----
  {
    int p = pA, hh = hhA;
    float qv[10];
    #pragma unroll
    for (int d = 0; d < 10; ++d) qv[d] = qa[p * 84 + hh * 10 + d];
    float sv[8];
    float denom = 0.f;
    #pragma unroll
    for (int kk = 0; kk < 8; ++kk) {
      const float2* kr = reinterpret_cast<const float2*>(kb + (gbase + nb[kk]) * 80 + hh * 10);
      float acc = 0.f;
      #pragma unroll
      for (int d2 = 0; d2 < 5; ++d2) {
        float2 kv2 = kr[d2];
        acc = fmaf(qv[2 * d2], kv2.x, acc);
        acc = fmaf(qv[2 * d2 + 1], kv2.y, acc);
      }
      float s = acc * 0.31622776601683794f;
      s = fminf(fmaxf(s, -5.f), 5.f);
      s = expf(s);
      sv[kk] = s;
      denom += s;
    }
    float wV[10] = {0, 0, 0, 0, 0, 0, 0, 0, 0, 0};
    #pragma unroll
    for (int kk = 0; kk < 8; ++kk) {
      const float2* vr = reinterpret_cast<const float2*>(vb + (gbase + nb[kk]) * 80 + hh * 10);
      #pragma unroll
      for (int d2 = 0; d2 < 5; ++d2) {
        float2 vv = vr[d2];
        wV[2 * d2] = fmaf(sv[kk], vv.x, wV[2 * d2]);
        wV[2 * d2 + 1] = fmaf(sv[kk], vv.y, wV[2 * d2 + 1]);
      }
    }
    float dn = denom + 1e-6f;
    #pragma unroll
    for (int d2 = 0; d2 < 5; ++d2) {
      float x0 = wV[2 * d2] / dn;
      float x1 = wV[2 * d2 + 1] / dn;
      unsigned short h0, l0, h1, l1;
      splitbf(x0, h0, l0); splitbf(x1, h1, l1);
      int off = p * 168 + hh * 10 + 2 * d2;
      *reinterpret_cast<unsigned*>(&ahi[off]) = (unsigned)h0 | ((unsigned)h1 << 16);
      *reinterpret_cast<unsigned*>(&alo[off]) = (unsigned)l0 | ((unsigned)l1 << 16);
    }
  }
  __syncthreads();
  // ---- Wo MFMA (reads attn split) ----
  f32x4 o0 = {0.f, 0.f, 0.f, 0.f}, o1 = o0, o2 = o0;
  {
    #pragma unroll
    for (int ks = 0; ks < 3; ++ks) {
      int boff = bcol * 96 + ks * 32 + fq * 8;
      short8v bh = *reinterpret_cast<const short8v*>(WoH + boff);
      short8v bl = *reinterpret_cast<const short8v*>(WoL + boff);
      int a0 = (0 * 16 + fr) * 168 + ks * 32 + fq * 8;
      int a1 = (1 * 16 + fr) * 168 + ks * 32 + fq * 8;
      int a2 = (2 * 16 + fr) * 168 + ks * 32 + fq * 8;
      short8v ah0 = *reinterpret_cast<const short8v*>(ahi + a0);
      short8v al0 = *reinterpret_cast<const short8v*>(alo + a0);
      MF3(o0, ah0, al0, bh, bl);
      short8v ah1 = *reinterpret_cast<const short8v*>(ahi + a1);
      short8v al1 = *reinterpret_cast<const short8v*>(alo + a1);
      MF3(o1, ah1, al1, bh, bl);
      short8v ah2 = *reinterpret_cast<const short8v*>(ahi + a2);
      short8v al2 = *reinterpret_cast<const short8v*>(alo + a2);
      MF3(o2, ah2, al2, bh, bl);
    }
  }
  __syncthreads();  // all waves done READING attn split before h2 overwrites
  // ---- Wo epilogue: h2 = h + attn@Wo + bo -> qa f32 + split into ahi/alo ----
  {
    float bias = bo[bcol];
    #pragma unroll
    for (int j = 0; j < 4; ++j) {
      int r0 = fq * 4 + j;
      float h2v = h[(pbase + r0) * 80 + bcol] + o0[j] + bias;
      qa[r0 * 84 + bcol] = h2v;
      unsigned short hh_, ll_;
      splitbf(h2v, hh_, ll_);
      ahi[r0 * 168 + bcol] = hh_;
      alo[r0 * 168 + bcol] = ll_;
      int r1 = 16 + r0;
      h2v = h[(pbase + r1) * 80 + bcol] + o1[j] + bias;
      qa[r1 * 84 + bcol] = h2v;
      splitbf(h2v, hh_, ll_);
      ahi[r1 * 168 + bcol] = hh_;
      alo[r1 * 168 + bcol] = ll_;
      int r2 = 32 + r0;
      if (r2 < 40) {
        h2v = h[(pbase + r2) * 80 + bcol] + o2[j] + bias;
        qa[r2 * 84 + bcol] = h2v;
        splitbf(h2v, hh_, ll_);
        ahi[r2 * 168 + bcol] = hh_;
        alo[r2 * 168 + bcol] = ll_;
      }
    }
  }
  __syncthreads();
  // ---- W1 MFMA: ts = relu(h2 @ W1 + b1), N=160 -> two col-tiles per wave ----
  f32x4 t00 = {0.f, 0.f, 0.f, 0.f}, t01 = t00, t02 = t00;  // ct = wv
  f32x4 t10 = t00, t11 = t00, t12 = t00;                   // ct = wv+5
  {
    int bc0 = wv * 16 + fr, bc1 = (wv + 5) * 16 + fr;
    #pragma unroll
    for (int ks = 0; ks < 3; ++ks) {
      int b0 = bc0 * 96 + ks * 32 + fq * 8;
      int b1o = bc1 * 96 + ks * 32 + fq * 8;
      short8v bh0 = *reinterpret_cast<const short8v*>(W1H + b0);
      short8v bl0 = *reinterpret_cast<const short8v*>(W1L + b0);
      short8v bh1 = *reinterpret_cast<const short8v*>(W1H + b1o);
      short8v bl1 = *reinterpret_cast<const short8v*>(W1L + b1o);
      int a0 = (0 * 16 + fr) * 168 + ks * 32 + fq * 8;
      int a1 = (1 * 16 + fr) * 168 + ks * 32 + fq * 8;
      int a2 = (2 * 16 + fr) * 168 + ks * 32 + fq * 8;
      short8v ah0 = *reinterpret_cast<const short8v*>(ahi + a0);
      short8v al0 = *reinterpret_cast<const short8v*>(alo + a0);
      MF3(t00, ah0, al0, bh0, bl0); MF3(t10, ah0, al0, bh1, bl1);
      short8v ah1 = *reinterpret_cast<const short8v*>(ahi + a1);
      short8v al1 = *reinterpret_cast<const short8v*>(alo + a1);
      MF3(t01, ah1, al1, bh0, bl0); MF3(t11, ah1, al1, bh1, bl1);
      short8v ah2 = *reinterpret_cast<const short8v*>(ahi + a2);
      short8v al2 = *reinterpret_cast<const short8v*>(alo + a2);
      MF3(t02, ah2, al2, bh0, bl0); MF3(t12, ah2, al2, bh1, bl1);
    }
  }
  __syncthreads();  // all waves done reading h2 split
  // ---- W1 epilogue: relu + split -> ahi/alo at k-positions = out col ----
  {
    int bc0 = wv * 16 + fr, bc1 = (wv + 5) * 16 + fr;
    float bias0 = b1[bc0], bias1 = b1[bc1];
    #pragma unroll
    for (int j = 0; j < 4; ++j) {
      unsigned short hh_, ll_;
      int r0 = fq * 4 + j;
      float t = fmaxf(t00[j] + bias0, 0.f);
      splitbf(t, hh_, ll_); ahi[r0 * 168 + bc0] = hh_; alo[r0 * 168 + bc0] = ll_;
      t = fmaxf(t10[j] + bias1, 0.f);
      splitbf(t, hh_, ll_); ahi[r0 * 168 + bc1] = hh_; alo[r0 * 168 + bc1] = ll_;
      int r1 = 16 + r0;
      t = fmaxf(t01[j] + bias0, 0.f);
      splitbf(t, hh_, ll_); ahi[r1 * 168 + bc0] = hh_; alo[r1 * 168 + bc0] = ll_;
      t = fmaxf(t11[j] + bias1, 0.f);
      splitbf(t, hh_, ll_); ahi[r1 * 168 + bc1] = hh_; alo[r1 * 168 + bc1] = ll_;
      int r2 = 32 + r0;
      if (r2 < 40) {
        t = fmaxf(t02[j] + bias0, 0.f);
        splitbf(t, hh_, ll_); ahi[r2 * 168 + bc0] = hh_; alo[r2 * 168 + bc0] = ll_;
        t = fmaxf(t12[j] + bias1, 0.f);
        splitbf(t, hh_, ll_); ahi[r2 * 168 + bc1] = hh_; alo[r2 * 168 + bc1] = ll_;
      }
    }
  }
  __syncthreads();
  // ---- W2 MFMA: out = h2 + ts @ W2 + b2, K=160 ----
  {
    f32x4 c0 = {0.f, 0.f, 0.f, 0.f}, c1 = c0, c2 = c0;
    #pragma unroll
    for (int ks = 0; ks < 5; ++ks) {
      int boff = bcol * 160 + ks * 32 + fq * 8;
      short8v bh = *reinterpret_cast<const short8v*>(W2H + boff);
      short8v bl = *reinterpret_cast<const short8v*>(W2L + boff);
      int a0 = (0 * 16 + fr) * 168 + ks * 32 + fq * 8;
      int a1 = (1 * 16 + fr) * 168 + ks * 32 + fq * 8;
      int a2 = (2 * 16 + fr) * 168 + ks * 32 + fq * 8;
      short8v ah0 = *reinterpret_cast<const short8v*>(ahi + a0);
      short8v al0 = *reinterpret_cast<const short8v*>(alo + a0);
      MF3(c0, ah0, al0, bh, bl);
      short8v ah1 = *reinterpret_cast<const short8v*>(ahi + a1);
      short8v al1 = *reinterpret_cast<const short8v*>(alo + a1);
      MF3(c1, ah1, al1, bh, bl);
      short8v ah2 = *reinterpret_cast<const short8v*>(ahi + a2);
      short8v al2 = *reinterpret_cast<const short8v*>(alo + a2);
      MF3(c2, ah2, al2, bh, bl);
    }
    float bias = b2[bcol];
    #pragma unroll
    for (int j = 0; j < 4; ++j) {
      int r0 = fq * 4 + j;
      hout[(pbase + r0) * 80 + bcol] = qa[r0 * 84 + bcol] + c0[j] + bias;
      int r1 = 16 + r0;
      hout[(pbase + r1) * 80 + bcol] = qa[r1 * 84 + bcol] + c1[j] + bias;
      int r2 = 32 + r0;
      if (r2 < 40) hout[(pbase + r2) * 80 + bcol] = qa[r2 * 84 + bcol] + c2[j] + bias;
    }
  }
}

// ---------------- Readout MLP 80->40->20->64->{3,1} (f32 vector, unchanged) ----------------
__global__ __launch_bounds__(320) void readout_kernel(const float* __restrict__ h, const float* __restrict__ Wr0,
                                                      const float* __restrict__ br0, const float* __restrict__ Wr1,
                                                      const float* __restrict__ br1, const float* __restrict__ Wr2,
                                                      const float* __restrict__ br2, const float* __restrict__ Wc,
                                                      const float* __restrict__ Wb, const float* __restrict__ bb,
                                                      float* __restrict__ out) {
  __shared__ __align__(16) float hs[3200];
  __shared__ __align__(16) float y0s[40 * 40];
  __shared__ __align__(16) float y1s[40 * 20];
  __shared__ __align__(16) float y2s[40 * 64];
  size_t p0 = (size_t)blockIdx.x * 40;
  int tid = threadIdx.x;
  {
    const float4* src = reinterpret_cast<const float4*>(h + p0 * 80);
    float4* dst = reinterpret_cast<float4*>(hs);
    for (int i = tid; i < 800; i += 320) dst[i] = src[i];
  }
  __syncthreads();
  {  // y0 = relu(h@Wr0 + br0)
    int c = tid % 40, grp = tid / 40;  // 0..7
    if (grp < 5) {
      float wcol[80];
      #pragma unroll
      for (int kk = 0; kk < 80; ++kk) wcol[kk] = Wr0[kk * 40 + c];
      float bias = br0[c];
      float acc[8] = {};
      #pragma unroll
      for (int j = 0; j < 8; ++j) {
        const float4* r4 = reinterpret_cast<const float4*>(hs + (grp * 8 + j) * 80);
        #pragma unroll
        for (int kq = 0; kq < 20; ++kq) {
          float4 hv = r4[kq];
          acc[j] = fmaf(hv.x, wcol[4 * kq + 0], acc[j]);
          acc[j] = fmaf(hv.y, wcol[4 * kq + 1], acc[j]);
          acc[j] = fmaf(hv.z, wcol[4 * kq + 2], acc[j]);
          acc[j] = fmaf(hv.w, wcol[4 * kq + 3], acc[j]);
        }
      }
      #pragma unroll
      for (int j = 0; j < 8; ++j) y0s[(grp * 8 + j) * 40 + c] = fmaxf(acc[j] + bias, 0.f);
    }
  }
  __syncthreads();
  {  // y1 = relu(y0@Wr1 + br1)
    int c = tid % 20, grp = tid / 20;  // 0..15
    if (grp < 5) {
      float wcol[40];
      #pragma unroll
      for (int kk = 0; kk < 40; ++kk) wcol[kk] = Wr1[kk * 20 + c];
      float bias = br1[c];
      float acc[8] = {};
      #pragma unroll
      for (int j = 0; j < 8; ++j) {
        const float4* r4 = reinterpret_cast<const float4*>(y0s + (grp * 8 + j) * 40);
        #pragma unroll
        for (int kq = 0; kq < 10; ++kq) {
          float4 hv = r4[kq];
          acc[j] = fmaf(hv.x, wcol[4 * kq + 0], acc[j]);
          acc[j] = fmaf(hv.y, wcol[4 * kq + 1], acc[j]);
          acc[j] = fmaf(hv.z, wcol[4 * kq + 2], acc[j]);
          acc[j] = fmaf(hv.w, wcol[4 * kq + 3], acc[j]);
        }
      }
      #pragma unroll
      for (int j = 0; j < 8; ++j) y1s[(grp * 8 + j) * 20 + c] = fmaxf(acc[j] + bias, 0.f);
    }
  }
  __syncthreads();
  {  // y2 = y1@Wr2 + br2
    int c = tid % 64, grp = tid / 64;  // 0..4
    float wcol[20];
    #pragma unroll
    for (int kk = 0; kk < 20; ++kk) wcol[kk] = Wr2[kk * 64 + c];
    float bias = br2[c];
    float acc[8] = {};
    #pragma unroll
    for (int j = 0; j < 8; ++j) {
      const float4* r4 = reinterpret_cast<const float4*>(y1s + (grp * 8 + j) * 20);
      #pragma unroll
      for (int kq = 0; kq < 5; ++kq) {
        float4 hv = r4[kq];
        acc[j] = fmaf(hv.x, wcol[4 * kq + 0], acc[j]);
        acc[j] = fmaf(hv.y, wcol[4 * kq + 1], acc[j]);
        acc[j] = fmaf(hv.z, wcol[4 * kq + 2], acc[j]);
        acc[j] = fmaf(hv.w, wcol[4 * kq + 3], acc[j]);
      }
    }
    #pragma unroll
    for (int j = 0; j < 8; ++j) y2s[(grp * 8 + j) * 64 + c] = acc[j] + bias;
  }
  __syncthreads();
  {  // out: cc = y2@Wc, beta = y2@Wb + bb
    int c = tid % 4, p = tid / 4;
    if (p < 40) {
      float wcol[64];
      if (c < 3) {
        #pragma unroll
        for (int kk = 0; kk < 64; ++kk) wcol[kk] = Wc[kk * 3 + c];
      } else {
        #pragma unroll
        for (int kk = 0; kk < 64; ++kk) wcol[kk] = Wb[kk];
      }
      float acc = 0.f;
      #pragma unroll
      for (int kk = 0; kk < 64; ++kk) acc = fmaf(y2s[p * 64 + kk], wcol[kk], acc);
      if (c == 3) acc += bb[0];
      out[(p0 + p) * 4 + c] = acc;
    }
  }
}

extern "C" void kernel_launch(void* const* d_in, const int* in_sizes, int n_in,
                              void* d_out, int out_size, void* d_ws, size_t ws_size,
                              hipStream_t stream) {
  const float* hf = (const float*)d_in[0];
  const float* gamma = (const float*)d_in[1];
  const float* beta = (const float*)d_in[2];
  const float* We = (const float*)d_in[3];
  const float* be = (const float*)d_in[4];
  const float* Wq = (const float*)d_in[5];
  const float* Wk = (const float*)d_in[6];
  const float* Wv = (const float*)d_in[7];
  const float* Wo = (const float*)d_in[8];
  const float* bo = (const float*)d_in[9];
  const float* W1 = (const float*)d_in[10];
  const float* b1 = (const float*)d_in[11];
  const float* W2 = (const float*)d_in[12];
  const float* b2 = (const float*)d_in[13];
  const float* Wr0 = (const float*)d_in[14];
  const float* br0 = (const float*)d_in[15];
  const float* Wr1 = (const float*)d_in[16];
  const float* br1 = (const float*)d_in[17];
  const float* Wr2 = (const float*)d_in[18];
  const float* br2 = (const float*)d_in[19];
  const float* Wc = (const float*)d_in[20];
  const float* Wb = (const float*)d_in[21];
  const float* bb = (const float*)d_in[22];
  float* out = (float*)d_out;

  char* wsp = (char*)d_ws;
  int* nbr = (int*)wsp;            wsp += (size_t)256000 * 8 * 4;
  float* hA = (float*)wsp;         wsp += (size_t)256000 * 80 * 4;
  float* kbuf = (float*)wsp;       wsp += (size_t)256000 * 80 * 4;
  float* vbuf = (float*)wsp;       wsp += (size_t)256000 * 80 * 4;
  float* partial = (float*)wsp;    wsp += (size_t)1000 * 18 * 4;
  float* stats = (float*)wsp;      wsp += 128;  // 18 floats = 72 B (keep 16B align)
  // split-bf16 transposed weights [col][KS] per layer
  unsigned short* WqH = (unsigned short*)wsp; wsp += (size_t)10 * 7680 * 2;
  unsigned short* WqL = (unsigned short*)wsp; wsp += (size_t)10 * 7680 * 2;
  unsigned short* WkH = (unsigned short*)wsp; wsp += (size_t)10 * 7680 * 2;
  unsigned short* WkL = (unsigned short*)wsp; wsp += (size_t)10 * 7680 * 2;
  unsigned short* WvH = (unsigned short*)wsp; wsp += (size_t)10 * 7680 * 2;
  unsigned short* WvL = (unsigned short*)wsp; wsp += (size_t)10 * 7680 * 2;
  unsigned short* WoH = (unsigned short*)wsp; wsp += (size_t)10 * 7680 * 2;
  unsigned short* WoL = (unsigned short*)wsp; wsp += (size_t)10 * 7680 * 2;
  unsigned short* W1H = (unsigned short*)wsp; wsp += (size_t)10 * 15360 * 2;
  unsigned short* W1L = (unsigned short*)wsp; wsp += (size_t)10 * 15360 * 2;
  unsigned short* W2H = (unsigned short*)wsp; wsp += (size_t)10 * 12800 * 2;
  unsigned short* W2L = (unsigned short*)wsp; wsp += (size_t)10 * 12800 * 2;

  knn_kernel<<<1024, 256, 0, stream>>>(hf, nbr);
  bn_stat1<<<1000, 256, 0, stream>>>(hf, partial);
  bn_stat2<<<1, 256, 0, stream>>>(partial, stats);
  split_tr<<<10, 256, 0, stream>>>(Wq, WqH, WqL, 80, 80, 96);
  split_tr<<<10, 256, 0, stream>>>(Wk, WkH, WkL, 80, 80, 96);
  split_tr<<<10, 256, 0, stream>>>(Wv, WvH, WvL, 80, 80, 96);
  split_tr<<<10, 256, 0, stream>>>(Wo, WoH, WoL, 80, 80, 96);
  split_tr<<<10, 256, 0, stream>>>(W1, W1H, W1L, 80, 160, 96);
  split_tr<<<10, 256, 0, stream>>>(W2, W2H, W2L, 160, 80, 160);
  embed_kernel<<<6400, 320, 0, stream>>>(hf, stats, gamma, beta, We, be, hA);
  for (int l = 0; l < 10; ++l) {
    kv_kernel<<<6400, 320, 0, stream>>>(hA, WkH + (size_t)l * 7680, WkL + (size_t)l * 7680,
                                        WvH + (size_t)l * 7680, WvL + (size_t)l * 7680, kbuf, vbuf);
    battn_kernel<<<6400, 320, 0, stream>>>(hA, kbuf, vbuf, nbr,
                                           WqH + (size_t)l * 7680, WqL + (size_t)l * 7680,
                                           WoH + (size_t)l * 7680, WoL + (size_t)l * 7680, bo + (size_t)l * 80,
                                           W1H + (size_t)l * 15360, W1L + (size_t)l * 15360, b1 + (size_t)l * 160,
                                           W2H + (size_t)l * 12800, W2L + (size_t)l * 12800, b2 + (size_t)l * 80, hA);
  }
  readout_kernel<<<6400, 320, 0, stream>>>(hA, Wr0, br0, Wr1, br1, Wr2, br2, Wc, Wb, bb, out);
}